// Round 4
// baseline (4305.353 us; speedup 1.0000x reference)
//
#include <hip/hip_runtime.h>
#include <hip/hip_bf16.h>
#include <math.h>
#include <float.h>

#define BNS_C 0.9999950000374996f /* 1/sqrt(1+1e-5) */

// ---------------- per-point squared norms; i over B*N, N=1024 ----------------
__global__ void k_sqnorm(const float* __restrict__ x, float* __restrict__ xx, int C) {
    int i = blockIdx.x * 256 + threadIdx.x;
    int b = i >> 10, n = i & 1023;
    const float* xb = x + ((size_t)b * C << 10);
    float s = 0.f;
    for (int c = 0; c < C; ++c) { float v = xb[(c << 10) + n]; s += v * v; }
    xx[i] = s;
}

// D_local[z][n][m] = 2*inner - xx[n] - xx[m]; z = batch - b0 (chunk of 2 batches)
__global__ __launch_bounds__(256) void k_gram(const float* __restrict__ x, const float* __restrict__ xx,
                                              float* __restrict__ D, int C, int b0) {
    const int N = 1024;
    int z = blockIdx.z;
    int b = b0 + z;
    int n0 = blockIdx.y * 64, m0 = blockIdx.x * 64;
    __shared__ float As[8][64], Bs[8][64];
    int tid = threadIdx.x;
    int ti = tid & 15;
    int tj = tid >> 4;
    float acc[4][4] = {};
    const float* xb = x + (size_t)b * C * N;
    for (int c0 = 0; c0 < C; c0 += 8) {
        for (int e = tid; e < 512; e += 256) {
            int cc = e >> 6, p = e & 63;
            int c = c0 + cc;
            As[cc][p] = (c < C) ? xb[c * N + n0 + p] : 0.f;
            Bs[cc][p] = (c < C) ? xb[c * N + m0 + p] : 0.f;
        }
        __syncthreads();
#pragma unroll
        for (int cc = 0; cc < 8; ++cc) {
            float av[4], bv[4];
#pragma unroll
            for (int a = 0; a < 4; ++a) av[a] = As[cc][tj + 16 * a];
#pragma unroll
            for (int q = 0; q < 4; ++q) bv[q] = Bs[cc][ti + 16 * q];
#pragma unroll
            for (int a = 0; a < 4; ++a)
#pragma unroll
                for (int q = 0; q < 4; ++q) acc[a][q] += av[a] * bv[q];
        }
        __syncthreads();
    }
#pragma unroll
    for (int a = 0; a < 4; ++a) {
        int n = n0 + tj + 16 * a;
        float xn = xx[b * N + n];
#pragma unroll
        for (int q = 0; q < 4; ++q) {
            int m = m0 + ti + 16 * q;
            float xm = xx[b * N + m];
            D[((size_t)((z << 10) + n) << 10) + m] = 2.f * acc[a][q] - xn - xm;
        }
    }
}

// top-20 per row, one wave per row; rows chunk-local, output offset by b0*1024
__global__ __launch_bounds__(256) void k_topk(const float* __restrict__ D, int* __restrict__ idxo, int b0) {
    const int K = 20;
    int lane = threadIdx.x & 63;
    int rl = blockIdx.x * 4 + (threadIdx.x >> 6);
    const float* row = D + ((size_t)rl << 10);
    float d[16];
#pragma unroll
    for (int j = 0; j < 16; ++j) d[j] = row[lane + 64 * j];
    int rg = (b0 << 10) + rl;
    for (int it = 0; it < K; ++it) {
        float bv = d[0]; int bj = 0;
#pragma unroll
        for (int j = 1; j < 16; ++j) if (d[j] > bv) { bv = d[j]; bj = j; }
        int bm = lane + (bj << 6);
        for (int off = 32; off > 0; off >>= 1) {
            float ov = __shfl_down(bv, off);
            int   om = __shfl_down(bm, off);
            if (ov > bv || (ov == bv && om < bm)) { bv = ov; bm = om; }
        }
        bm = __shfl(bm, 0);
        if (lane == 0) idxo[rg * K + it] = bm;
        if ((bm & 63) == lane) d[bm >> 6] = -FLT_MAX;
    }
}

// ---------------- edge conv: y = W1*x_nbr + (W2-W1)*x_ctr ; BN+leaky ; max over k ----------------
__global__ __launch_bounds__(256) void k_edgeconv(const float* __restrict__ xin, const int* __restrict__ idx,
                                                  const float* __restrict__ w,
                                                  const float* __restrict__ gg,
                                                  const float* __restrict__ bb,
                                                  float* __restrict__ xout, int C, int O) {
    extern __shared__ float smem[];
    const int K = 20;
    int Cp = (C + 3) & ~3;
    int G = 256 / O;
    int S = K * Cp + 4;
    float* xn = smem;              // [G][S]
    float* ctr = smem + G * S;     // [G][Cp]
    int tid = threadIdx.x;
    int nb0 = blockIdx.x * G;

    int total = G * K * Cp;
    for (int e = tid; e < total; e += 256) {
        int g = e / (K * Cp); int rem = e - g * (K * Cp);
        int k = rem / Cp;     int c = rem - k * Cp;
        int nb = nb0 + g; int b = nb >> 10;
        float v = 0.f;
        if (c < C) {
            int m = idx[nb * K + k] & 1023;
            v = xin[((size_t)(b * C + c) << 10) + m];
        }
        xn[g * S + k * Cp + c] = v;
    }
    for (int e = tid; e < G * Cp; e += 256) {
        int g = e / Cp; int c = e - g * Cp;
        int nb = nb0 + g; int b = nb >> 10; int n = nb & 1023;
        ctr[g * Cp + c] = (c < C) ? xin[((size_t)(b * C + c) << 10) + n] : 0.f;
    }
    __syncthreads();

    int o = tid / G, g = tid % G;
    int nb = nb0 + g, b = nb >> 10, n = nb & 1023;
    const float* wo = w + (size_t)o * 2 * C;

    float tc = 0.f;
    for (int c = 0; c < C; ++c) tc += ctr[g * Cp + c] * (wo[C + c] - wo[c]);
    float acc[20];
#pragma unroll
    for (int k = 0; k < 20; ++k) acc[k] = tc;

    const float* xng = xn + g * S;
    for (int c0 = 0; c0 < Cp; c0 += 4) {
        float w0 = (c0 + 0 < C) ? wo[c0 + 0] : 0.f;
        float w1 = (c0 + 1 < C) ? wo[c0 + 1] : 0.f;
        float w2 = (c0 + 2 < C) ? wo[c0 + 2] : 0.f;
        float w3 = (c0 + 3 < C) ? wo[c0 + 3] : 0.f;
#pragma unroll
        for (int k = 0; k < 20; ++k) {
            const float4 v = *(const float4*)(xng + k * Cp + c0);
            acc[k] += v.x * w0 + v.y * w1 + v.z * w2 + v.w * w3;
        }
    }
    float gv = gg[o], bv = bb[o];
    float mx = -FLT_MAX;
#pragma unroll
    for (int k = 0; k < 20; ++k) {
        float y = gv * (acc[k] * BNS_C) + bv;
        y = y > 0.f ? y : 0.2f * y;
        mx = fmaxf(mx, y);
    }
    xout[((size_t)(b * O + o) << 10) + n] = mx;
}

// ---------------- w5 conv (1024x512) fused with BN+leaky and max/mean pool over n ----------------
__global__ __launch_bounds__(256) void k_final(const float* __restrict__ x1, const float* __restrict__ x2,
                                               const float* __restrict__ x3, const float* __restrict__ x4,
                                               const float* __restrict__ w5,
                                               const float* __restrict__ g5,
                                               const float* __restrict__ b5,
                                               float* __restrict__ p) {
    __shared__ float wt[16][512];
    __shared__ float red[4][16][2];
    int b = blockIdx.y;
    int o0 = blockIdx.x * 16;
    int tid = threadIdx.x;
    for (int e = tid; e < 16 * 512; e += 256) {
        int oi = e >> 9, c = e & 511;
        wt[oi][c] = w5[(size_t)(o0 + oi) * 512 + c];
    }
    __syncthreads();
    float acc[16][4] = {};
    const float* srcs[4] = {x1, x2, x3, x4};
    const int cs[4] = {64, 64, 128, 256};
    int ct = 0;
    for (int s = 0; s < 4; ++s) {
        const float* src = srcs[s] + ((size_t)b * cs[s] << 10);
        for (int c = 0; c < cs[s]; ++c) {
            float h0 = src[(c << 10) + tid];
            float h1 = src[(c << 10) + tid + 256];
            float h2 = src[(c << 10) + tid + 512];
            float h3 = src[(c << 10) + tid + 768];
#pragma unroll
            for (int oi = 0; oi < 16; ++oi) {
                float wv = wt[oi][ct];
                acc[oi][0] += wv * h0; acc[oi][1] += wv * h1;
                acc[oi][2] += wv * h2; acc[oi][3] += wv * h3;
            }
            ++ct;
        }
    }
    int lane = tid & 63, wid = tid >> 6;
#pragma unroll
    for (int oi = 0; oi < 16; ++oi) {
        float gv = g5[o0 + oi];
        float bv = b5[o0 + oi];
        float mx = -FLT_MAX, sm = 0.f;
#pragma unroll
        for (int j = 0; j < 4; ++j) {
            float y = gv * (acc[oi][j] * BNS_C) + bv;
            y = y > 0.f ? y : 0.2f * y;
            mx = fmaxf(mx, y); sm += y;
        }
        for (int off = 32; off; off >>= 1) {
            mx = fmaxf(mx, __shfl_down(mx, off));
            sm += __shfl_down(sm, off);
        }
        if (lane == 0) { red[wid][oi][0] = mx; red[wid][oi][1] = sm; }
    }
    __syncthreads();
    if (tid < 16) {
        float mx = fmaxf(fmaxf(red[0][tid][0], red[1][tid][0]), fmaxf(red[2][tid][0], red[3][tid][0]));
        float sm = red[0][tid][1] + red[1][tid][1] + red[2][tid][1] + red[3][tid][1];
        p[b * 2048 + o0 + tid] = mx;
        p[b * 2048 + 1024 + o0 + tid] = sm * (1.f / 1024.f);
    }
}

// ---------------- small FC ----------------
__global__ void k_fc(const float* __restrict__ in, const float* __restrict__ w,
                     const float* __restrict__ gg, const float* __restrict__ bb,
                     float* __restrict__ out,
                     int R, int C, int O, int act) {
    int i = blockIdx.x * 256 + threadIdx.x;
    if (i >= R * O) return;
    int r = i / O, o = i - r * O;
    const float* ir = in + (size_t)r * C;
    const float* wr = w + (size_t)o * C;
    float s = 0.f;
    for (int c = 0; c < C; ++c) s += ir[c] * wr[c];
    float y = s;
    if (gg) y = gg[o] * (s * BNS_C) + bb[o];
    if (act == 1) y = y > 0.f ? y : 0.2f * y;
    else if (act == 2) y = 0.5f * y * (1.f + erff(y * 0.70710678118654752f));
    out[i] = y;
}

extern "C" void kernel_launch(void* const* d_in, const int* in_sizes, int n_in,
                              void* d_out, int out_size, void* d_ws, size_t ws_size,
                              hipStream_t stream) {
    typedef const float* fp;
    fp xf = (fp)d_in[0];
    fp w1 = (fp)d_in[2],  g1 = (fp)d_in[3],  b1 = (fp)d_in[4];
    fp w2 = (fp)d_in[5],  g2 = (fp)d_in[6],  b2 = (fp)d_in[7];
    fp w3 = (fp)d_in[8],  g3 = (fp)d_in[9],  b3 = (fp)d_in[10];
    fp w4 = (fp)d_in[11], g4 = (fp)d_in[12], b4 = (fp)d_in[13];
    fp w5 = (fp)d_in[14], g5 = (fp)d_in[15], b5 = (fp)d_in[16];
    fp wl1 = (fp)d_in[17], g6 = (fp)d_in[18], b6 = (fp)d_in[19];
    fp wl2 = (fp)d_in[20], g7 = (fp)d_in[21], b7 = (fp)d_in[22];
    fp wl21 = (fp)d_in[23], wl22 = (fp)d_in[24];
    fp g8 = (fp)d_in[25], b8 = (fp)d_in[26], wl3 = (fp)d_in[27];

    char* ws = (char*)d_ws;
    size_t off = 0;
    auto alloc = [&](size_t floats) { float* p_ = (float*)(ws + off); off += floats * 4; off = (off + 255) & ~(size_t)255; return p_; };
    float* x1  = alloc(1048576);      // 16*64*1024
    float* x2  = alloc(1048576);
    float* x3  = alloc(2097152);      // 16*128*1024
    float* x4  = alloc(4194304);      // 16*256*1024
    float* D   = alloc(2097152);      // 2 batches * 1024 * 1024 (chunked)
    float* xx  = alloc(16384);
    int*   nbr = (int*)alloc(327680); // 16*1024*20 ints
    float* p   = alloc(32768);        // 16*2048
    float* z1  = alloc(4096);
    float* z2  = alloc(2048);
    float* zt  = alloc(1024);
    float* z3  = alloc(512);
    // total ~41 MB

    struct Blk { const float* xin; int C; int O; const float *w, *g, *b; float* xout; };
    Blk blks[4] = {
        {xf, 6,   64,  w1, g1, b1, x1},
        {x1, 64,  64,  w2, g2, b2, x2},
        {x2, 64,  128, w3, g3, b3, x3},
        {x3, 128, 256, w4, g4, b4, x4},
    };
    for (int i = 0; i < 4; ++i) {
        const Blk& B_ = blks[i];
        k_sqnorm<<<64, 256, 0, stream>>>(B_.xin, xx, B_.C);
        for (int b0 = 0; b0 < 16; b0 += 2) {
            k_gram<<<dim3(16, 16, 2), 256, 0, stream>>>(B_.xin, xx, D, B_.C, b0);
            k_topk<<<512, 256, 0, stream>>>(D, nbr, b0);
        }
        int Cp = (B_.C + 3) & ~3;
        int G = 256 / B_.O;
        int S = 20 * Cp + 4;
        size_t lds = (size_t)(G * S + G * Cp) * 4;
        k_edgeconv<<<16384 / G, 256, lds, stream>>>(B_.xin, nbr, B_.w, B_.g, B_.b, B_.xout, B_.C, B_.O);
    }

    k_final<<<dim3(64, 16), 256, 0, stream>>>(x1, x2, x3, x4, w5, g5, b5, p);

    k_fc<<<(16 * 256 + 255) / 256, 256, 0, stream>>>(p,  wl1, g6, b6, z1, 16, 2048, 256, 1);
    k_fc<<<(16 * 128 + 255) / 256, 256, 0, stream>>>(z1, wl2, g7, b7, z2, 16, 256, 128, 1);
    k_fc<<<(16 * 64  + 255) / 256, 256, 0, stream>>>(z2, wl21, nullptr, nullptr, zt, 16, 128, 64, 0);
    k_fc<<<(16 * 32  + 255) / 256, 256, 0, stream>>>(zt, wl22, g8, b8, z3, 16, 64, 32, 2);
    k_fc<<<(16 * 90  + 255) / 256, 256, 0, stream>>>(z3, wl3, nullptr, nullptr, (float*)d_out, 16, 32, 90, 0);
}

// Round 5
// 1514.136 us; speedup vs baseline: 2.8434x; 2.8434x over previous
//
#include <hip/hip_runtime.h>
#include <math.h>
#include <float.h>

#define BNS_C 0.9999950000374996f /* 1/sqrt(1+1e-5) */

// ---------------- x[b][6][1024] -> X0[b][n][8] (zero-padded) ----------------
__global__ void k_xin_t(const float* __restrict__ x, float* __restrict__ X0) {
    int i = blockIdx.x * 256 + threadIdx.x;   // over 16384 points
    int b = i >> 10, n = i & 1023;
    const float* xb = x + (((size_t)b * 6) << 10) + n;
    float4* o4 = (float4*)(X0 + ((size_t)i << 3));
    float v0 = xb[0], v1 = xb[1 << 10], v2 = xb[2 << 10];
    float v3 = xb[3 << 10], v4 = xb[4 << 10], v5 = xb[5 << 10];
    o4[0] = make_float4(v0, v1, v2, v3);
    o4[1] = make_float4(v4, v5, 0.f, 0.f);
}

// ---------------- xx[b*1024+n] = sum_c X[b][n][c]^2 (pads are zero) ----------------
__global__ void k_sqnorm2(const float* __restrict__ X, float* __restrict__ xx, int Cp) {
    int i = blockIdx.x * 256 + threadIdx.x;
    const float4* r = (const float4*)(X + (size_t)i * Cp);
    float s = 0.f;
    for (int c4 = 0; c4 < (Cp >> 2); ++c4) {
        float4 v = r[c4];
        s += v.x * v.x + v.y * v.y + v.z * v.z + v.w * v.w;
    }
    xx[i] = s;
}

// ---- D[z][n][m] = 2*X[n]·X[m] - xx[n] - xx[m], X point-major; chunk of 8 batches ----
__global__ __launch_bounds__(256) void k_gram2(const float* __restrict__ X, const float* __restrict__ xx,
                                               float* __restrict__ D, int Cp, int b0) {
    int z = blockIdx.z, b = b0 + z;
    int n0 = blockIdx.y * 64, m0 = blockIdx.x * 64;
    __shared__ float As[64][33], Bs[64][33];
    int tid = threadIdx.x;
    int ti = tid & 15, tj = tid >> 4;
    float acc[4][4] = {};
    const float* Xb = X + (((size_t)b) << 10) * Cp;
    for (int c0 = 0; c0 < Cp; c0 += 32) {
        for (int e = tid; e < 2048; e += 256) {
            int row = e >> 5, cc = e & 31, c = c0 + cc;
            float a = 0.f, bb = 0.f;
            if (c < Cp) {
                a  = Xb[(size_t)(n0 + row) * Cp + c];
                bb = Xb[(size_t)(m0 + row) * Cp + c];
            }
            As[row][cc] = a; Bs[row][cc] = bb;
        }
        __syncthreads();
#pragma unroll 8
        for (int cc = 0; cc < 32; ++cc) {
            float xv[4], yv[4];
#pragma unroll
            for (int a = 0; a < 4; ++a) xv[a] = As[tj + 16 * a][cc];
#pragma unroll
            for (int q = 0; q < 4; ++q) yv[q] = Bs[ti + 16 * q][cc];
#pragma unroll
            for (int a = 0; a < 4; ++a)
#pragma unroll
                for (int q = 0; q < 4; ++q) acc[a][q] += xv[a] * yv[q];
        }
        __syncthreads();
    }
#pragma unroll
    for (int a = 0; a < 4; ++a) {
        int n = n0 + tj + 16 * a;
        float xn = xx[(b << 10) + n];
#pragma unroll
        for (int q = 0; q < 4; ++q) {
            int m = m0 + ti + 16 * q;
            D[((size_t)((z << 10) + n) << 10) + m] = 2.f * acc[a][q] - xn - xx[(b << 10) + m];
        }
    }
}

// ---------------- top-20 per row, one wave per row (rows chunk-local) ----------------
__global__ __launch_bounds__(256) void k_topk(const float* __restrict__ D, int* __restrict__ idxo, int b0) {
    const int K = 20;
    int lane = threadIdx.x & 63;
    int rl = blockIdx.x * 4 + (threadIdx.x >> 6);
    const float* row = D + ((size_t)rl << 10);
    float d[16];
#pragma unroll
    for (int j = 0; j < 16; ++j) d[j] = row[lane + 64 * j];
    int rg = (b0 << 10) + rl;
    for (int it = 0; it < K; ++it) {
        float bv = d[0]; int bj = 0;
#pragma unroll
        for (int j = 1; j < 16; ++j) if (d[j] > bv) { bv = d[j]; bj = j; }
        int bm = lane + (bj << 6);
        for (int off = 32; off > 0; off >>= 1) {
            float ov = __shfl_down(bv, off);
            int   om = __shfl_down(bm, off);
            if (ov > bv || (ov == bv && om < bm)) { bv = ov; bm = om; }
        }
        bm = __shfl(bm, 0);
        if (lane == 0) idxo[rg * K + it] = bm;
        if ((bm & 63) == lane) d[bm >> 6] = -FLT_MAX;
    }
}

// ---- V[b][n][o] = X·Wa^T, U[b][n][o] = X·(Wb-Wa)^T ; w is [O][2C] ----
__global__ __launch_bounds__(256) void k_uv(const float* __restrict__ X, const float* __restrict__ w,
                                            float* __restrict__ V, float* __restrict__ U,
                                            int Cp, int C, int O) {
    int n0 = blockIdx.x * 64, o0 = blockIdx.y * 64, b = blockIdx.z;
    __shared__ float Xs[64][33], Was[64][33], Wds[64][33];
    int tid = threadIdx.x, ti = tid & 15, tj = tid >> 4;
    float accv[4][4] = {}, accu[4][4] = {};
    const float* Xb = X + (((size_t)b) << 10) * Cp;
    int W2 = 2 * C;
    for (int c0 = 0; c0 < Cp; c0 += 32) {
        for (int e = tid; e < 2048; e += 256) {
            int row = e >> 5, cc = e & 31, c = c0 + cc;
            Xs[row][cc] = (c < Cp) ? Xb[(size_t)(n0 + row) * Cp + c] : 0.f;
            float wa = 0.f, wd = 0.f;
            if (c < C) {
                float a_ = w[(size_t)(o0 + row) * W2 + c];
                float b_ = w[(size_t)(o0 + row) * W2 + C + c];
                wa = a_; wd = b_ - a_;
            }
            Was[row][cc] = wa; Wds[row][cc] = wd;
        }
        __syncthreads();
#pragma unroll 8
        for (int cc = 0; cc < 32; ++cc) {
            float xv[4], av[4], dv[4];
#pragma unroll
            for (int a = 0; a < 4; ++a) xv[a] = Xs[tj + 16 * a][cc];
#pragma unroll
            for (int q = 0; q < 4; ++q) { av[q] = Was[ti + 16 * q][cc]; dv[q] = Wds[ti + 16 * q][cc]; }
#pragma unroll
            for (int a = 0; a < 4; ++a)
#pragma unroll
                for (int q = 0; q < 4; ++q) { accv[a][q] += xv[a] * av[q]; accu[a][q] += xv[a] * dv[q]; }
        }
        __syncthreads();
    }
#pragma unroll
    for (int a = 0; a < 4; ++a) {
        int n = n0 + tj + 16 * a;
#pragma unroll
        for (int q = 0; q < 4; ++q) {
            int o = o0 + ti + 16 * q;
            size_t oi = ((size_t)((b << 10) + n)) * O + o;
            V[oi] = accv[a][q]; U[oi] = accu[a][q];
        }
    }
}

// ---- out[b][n][o] = max_k leaky(bn(V[b][m_k][o] + U[b][n][o])) ; coalesced rows ----
__global__ __launch_bounds__(256) void k_gmax(const float* __restrict__ V, const float* __restrict__ U,
                                              const int* __restrict__ idx,
                                              const float* __restrict__ gg, const float* __restrict__ bb,
                                              float* __restrict__ Xo, int O) {
    int tid = threadIdx.x;
    int Tn = 256 / O;
    int j = tid / O, o = tid - j * O;
    int pt = blockIdx.x * Tn + j;          // global point = b*1024+n
    int b = pt >> 10;
    float uv = U[(size_t)pt * O + o];
    float gv = gg[o], bv = bb[o];
    const int* ip = idx + (size_t)pt * 20;
    float mx = -FLT_MAX;
    for (int k = 0; k < 20; ++k) {
        int m = ip[k] & 1023;
        float vv = V[(size_t)((b << 10) + m) * O + o];
        float y = gv * ((vv + uv) * BNS_C) + bv;
        y = y > 0.f ? y : 0.2f * y;
        mx = fmaxf(mx, y);
    }
    Xo[(size_t)pt * O + o] = mx;
}

// ---------------- tiled transpose X[b][1024][C] -> T[b][C][1024] ----------------
__global__ __launch_bounds__(256) void k_ht(const float* __restrict__ X, float* __restrict__ T, int C) {
    int b = blockIdx.z;
    int n0 = blockIdx.x * 32, c0 = blockIdx.y * 32;
    __shared__ float t[32][33];
    int tid = threadIdx.x;
    int cc = tid & 31, r = tid >> 5;
#pragma unroll
    for (int p = 0; p < 4; ++p) {
        int row = p * 8 + r;
        t[row][cc] = X[(size_t)((b << 10) + n0 + row) * C + c0 + cc];
    }
    __syncthreads();
#pragma unroll
    for (int p = 0; p < 4; ++p) {
        int crow = p * 8 + r;
        T[((size_t)(b * C + c0 + crow) << 10) + n0 + cc] = t[cc][crow];
    }
}

// ---------------- w5 conv fused with BN+leaky and max/mean pool over n ----------------
__global__ __launch_bounds__(256) void k_final(const float* __restrict__ x1, const float* __restrict__ x2,
                                               const float* __restrict__ x3, const float* __restrict__ x4,
                                               const float* __restrict__ w5,
                                               const float* __restrict__ g5,
                                               const float* __restrict__ b5,
                                               float* __restrict__ p) {
    __shared__ float wt[16][512];
    __shared__ float red[4][16][2];
    int b = blockIdx.y;
    int o0 = blockIdx.x * 16;
    int tid = threadIdx.x;
    for (int e = tid; e < 16 * 512; e += 256) {
        int oi = e >> 9, c = e & 511;
        wt[oi][c] = w5[(size_t)(o0 + oi) * 512 + c];
    }
    __syncthreads();
    float acc[16][4] = {};
    const float* srcs[4] = {x1, x2, x3, x4};
    const int cs[4] = {64, 64, 128, 256};
    int ct = 0;
    for (int s = 0; s < 4; ++s) {
        const float* src = srcs[s] + (((size_t)b * cs[s]) << 10);
        for (int c = 0; c < cs[s]; ++c) {
            float h0 = src[(c << 10) + tid];
            float h1 = src[(c << 10) + tid + 256];
            float h2 = src[(c << 10) + tid + 512];
            float h3 = src[(c << 10) + tid + 768];
#pragma unroll
            for (int oi = 0; oi < 16; ++oi) {
                float wv = wt[oi][ct];
                acc[oi][0] += wv * h0; acc[oi][1] += wv * h1;
                acc[oi][2] += wv * h2; acc[oi][3] += wv * h3;
            }
            ++ct;
        }
    }
    int lane = tid & 63, wid = tid >> 6;
#pragma unroll
    for (int oi = 0; oi < 16; ++oi) {
        float gv = g5[o0 + oi];
        float bv = b5[o0 + oi];
        float mx = -FLT_MAX, sm = 0.f;
#pragma unroll
        for (int j = 0; j < 4; ++j) {
            float y = gv * (acc[oi][j] * BNS_C) + bv;
            y = y > 0.f ? y : 0.2f * y;
            mx = fmaxf(mx, y); sm += y;
        }
        for (int off = 32; off; off >>= 1) {
            mx = fmaxf(mx, __shfl_down(mx, off));
            sm += __shfl_down(sm, off);
        }
        if (lane == 0) { red[wid][oi][0] = mx; red[wid][oi][1] = sm; }
    }
    __syncthreads();
    if (tid < 16) {
        float mx = fmaxf(fmaxf(red[0][tid][0], red[1][tid][0]), fmaxf(red[2][tid][0], red[3][tid][0]));
        float sm = red[0][tid][1] + red[1][tid][1] + red[2][tid][1] + red[3][tid][1];
        p[b * 2048 + o0 + tid] = mx;
        p[b * 2048 + 1024 + o0 + tid] = sm * (1.f / 1024.f);
    }
}

// ---------------- small FC ----------------
__global__ void k_fc(const float* __restrict__ in, const float* __restrict__ w,
                     const float* __restrict__ gg, const float* __restrict__ bb,
                     float* __restrict__ out,
                     int R, int C, int O, int act) {
    int i = blockIdx.x * 256 + threadIdx.x;
    if (i >= R * O) return;
    int r = i / O, o = i - r * O;
    const float* ir = in + (size_t)r * C;
    const float* wr = w + (size_t)o * C;
    float s = 0.f;
    for (int c = 0; c < C; ++c) s += ir[c] * wr[c];
    float y = s;
    if (gg) y = gg[o] * (s * BNS_C) + bb[o];
    if (act == 1) y = y > 0.f ? y : 0.2f * y;
    else if (act == 2) y = 0.5f * y * (1.f + erff(y * 0.70710678118654752f));
    out[i] = y;
}

extern "C" void kernel_launch(void* const* d_in, const int* in_sizes, int n_in,
                              void* d_out, int out_size, void* d_ws, size_t ws_size,
                              hipStream_t stream) {
    typedef const float* fp;
    fp x  = (fp)d_in[0];
    fp w1 = (fp)d_in[2],  g1 = (fp)d_in[3],  b1 = (fp)d_in[4];
    fp w2 = (fp)d_in[5],  g2 = (fp)d_in[6],  b2 = (fp)d_in[7];
    fp w3 = (fp)d_in[8],  g3 = (fp)d_in[9],  b3 = (fp)d_in[10];
    fp w4 = (fp)d_in[11], g4 = (fp)d_in[12], b4 = (fp)d_in[13];
    fp w5 = (fp)d_in[14], g5 = (fp)d_in[15], b5 = (fp)d_in[16];
    fp wl1 = (fp)d_in[17], g6 = (fp)d_in[18], b6 = (fp)d_in[19];
    fp wl2 = (fp)d_in[20], g7 = (fp)d_in[21], b7 = (fp)d_in[22];
    fp wl21 = (fp)d_in[23], wl22 = (fp)d_in[24];
    fp g8 = (fp)d_in[25], b8 = (fp)d_in[26], wl3 = (fp)d_in[27];

    char* ws = (char*)d_ws;
    size_t off = 0;
    auto alloc = [&](size_t floats) { float* p_ = (float*)(ws + off); off += floats * 4; off = (off + 255) & ~(size_t)255; return p_; };
    float* X0  = alloc(131072);       // 16*1024*8
    float* X1  = alloc(1048576);      // [b][n][64]
    float* X2  = alloc(1048576);
    float* X3  = alloc(2097152);      // [b][n][128]
    float* X4  = alloc(4194304);      // [b][n][256]
    float* xx  = alloc(16384);
    int*   nbr = (int*)alloc(327680); // 16*1024*20
    float* pool = alloc(8388608);     // 32 MiB union: D(8b chunk) | V+U | T1..T4
    float* p   = alloc(32768);
    float* z1  = alloc(4096);
    float* z2  = alloc(2048);
    float* zt  = alloc(1024);
    float* z3  = alloc(512);
    // total ~66 MB

    float* D = pool;                       // 8*1024*1024
    float* V = pool;                       // up to 16384*256
    float* U = pool + 4194304;
    float* T1 = pool;                      // [b][64][1024]
    float* T2 = pool + 1048576;
    float* T3 = pool + 2097152;            // [b][128][1024]
    float* T4 = pool + 4194304;            // [b][256][1024]

    k_xin_t<<<64, 256, 0, stream>>>(x, X0);

    struct Blk { const float* Xin; int Cp, C, O; const float *w, *g, *b; float* Xout; };
    Blk blks[4] = {
        {X0, 8,   6,   64,  w1, g1, b1, X1},
        {X1, 64,  64,  64,  w2, g2, b2, X2},
        {X2, 64,  64,  128, w3, g3, b3, X3},
        {X3, 128, 128, 256, w4, g4, b4, X4},
    };
    for (int i = 0; i < 4; ++i) {
        const Blk& B_ = blks[i];
        k_sqnorm2<<<64, 256, 0, stream>>>(B_.Xin, xx, B_.Cp);
        for (int b0 = 0; b0 < 16; b0 += 8) {
            k_gram2<<<dim3(16, 16, 8), 256, 0, stream>>>(B_.Xin, xx, D, B_.Cp, b0);
            k_topk<<<2048, 256, 0, stream>>>(D, nbr, b0);
        }
        k_uv<<<dim3(16, B_.O / 64, 16), 256, 0, stream>>>(B_.Xin, B_.w, V, U, B_.Cp, B_.C, B_.O);
        int Tn = 256 / B_.O;
        k_gmax<<<16384 / Tn, 256, 0, stream>>>(V, U, nbr, B_.g, B_.b, B_.Xout, B_.O);
    }

    k_ht<<<dim3(32, 2, 16), 256, 0, stream>>>(X1, T1, 64);
    k_ht<<<dim3(32, 2, 16), 256, 0, stream>>>(X2, T2, 64);
    k_ht<<<dim3(32, 4, 16), 256, 0, stream>>>(X3, T3, 128);
    k_ht<<<dim3(32, 8, 16), 256, 0, stream>>>(X4, T4, 256);

    k_final<<<dim3(64, 16), 256, 0, stream>>>(T1, T2, T3, T4, w5, g5, b5, p);

    k_fc<<<(16 * 256 + 255) / 256, 256, 0, stream>>>(p,  wl1, g6, b6, z1, 16, 2048, 256, 1);
    k_fc<<<(16 * 128 + 255) / 256, 256, 0, stream>>>(z1, wl2, g7, b7, z2, 16, 256, 128, 1);
    k_fc<<<(16 * 64  + 255) / 256, 256, 0, stream>>>(z2, wl21, nullptr, nullptr, zt, 16, 128, 64, 0);
    k_fc<<<(16 * 32  + 255) / 256, 256, 0, stream>>>(zt, wl22, g8, b8, z3, 16, 64, 32, 2);
    k_fc<<<(16 * 90  + 255) / 256, 256, 0, stream>>>(z3, wl3, nullptr, nullptr, (float*)d_out, 16, 32, 90, 0);
}

// Round 6
// 1206.006 us; speedup vs baseline: 3.5699x; 1.2555x over previous
//
#include <hip/hip_runtime.h>
#include <math.h>
#include <float.h>

#define BNS_C 0.9999950000374996f /* 1/sqrt(1+1e-5) */

// ---------------- x[b][6][1024] -> X0[b][n][8] (zero-padded) ----------------
__global__ void k_xin_t(const float* __restrict__ x, float* __restrict__ X0) {
    int i = blockIdx.x * 256 + threadIdx.x;   // over 16384 points
    int b = i >> 10, n = i & 1023;
    const float* xb = x + (((size_t)b * 6) << 10) + n;
    float4* o4 = (float4*)(X0 + ((size_t)i << 3));
    float v0 = xb[0], v1 = xb[1 << 10], v2 = xb[2 << 10];
    float v3 = xb[3 << 10], v4 = xb[4 << 10], v5 = xb[5 << 10];
    o4[0] = make_float4(v0, v1, v2, v3);
    o4[1] = make_float4(v4, v5, 0.f, 0.f);
}

// ---------------- xx[b*1024+n] = sum_c X[b][n][c]^2 (pads are zero) ----------------
__global__ void k_sqnorm2(const float* __restrict__ X, float* __restrict__ xx, int Cp) {
    int i = blockIdx.x * 256 + threadIdx.x;
    const float4* r = (const float4*)(X + (size_t)i * Cp);
    float s = 0.f;
    for (int c4 = 0; c4 < (Cp >> 2); ++c4) {
        float4 v = r[c4];
        s += v.x * v.x + v.y * v.y + v.z * v.z + v.w * v.w;
    }
    xx[i] = s;
}

// ---- D[z][n][m] = 2*X[n]·X[m] - xx[n] - xx[m], X point-major; chunk of 8 batches ----
__global__ __launch_bounds__(256) void k_gram2(const float* __restrict__ X, const float* __restrict__ xx,
                                               float* __restrict__ D, int Cp, int b0) {
    int z = blockIdx.z, b = b0 + z;
    int n0 = blockIdx.y * 64, m0 = blockIdx.x * 64;
    __shared__ float As[64][33], Bs[64][33];
    int tid = threadIdx.x;
    int ti = tid & 15, tj = tid >> 4;
    float acc[4][4] = {};
    const float* Xb = X + (((size_t)b) << 10) * Cp;
    for (int c0 = 0; c0 < Cp; c0 += 32) {
        for (int e = tid; e < 2048; e += 256) {
            int row = e >> 5, cc = e & 31, c = c0 + cc;
            float a = 0.f, bb = 0.f;
            if (c < Cp) {
                a  = Xb[(size_t)(n0 + row) * Cp + c];
                bb = Xb[(size_t)(m0 + row) * Cp + c];
            }
            As[row][cc] = a; Bs[row][cc] = bb;
        }
        __syncthreads();
#pragma unroll 8
        for (int cc = 0; cc < 32; ++cc) {
            float xv[4], yv[4];
#pragma unroll
            for (int a = 0; a < 4; ++a) xv[a] = As[tj + 16 * a][cc];
#pragma unroll
            for (int q = 0; q < 4; ++q) yv[q] = Bs[ti + 16 * q][cc];
#pragma unroll
            for (int a = 0; a < 4; ++a)
#pragma unroll
                for (int q = 0; q < 4; ++q) acc[a][q] += xv[a] * yv[q];
        }
        __syncthreads();
    }
#pragma unroll
    for (int a = 0; a < 4; ++a) {
        int n = n0 + tj + 16 * a;
        float xn = xx[(b << 10) + n];
#pragma unroll
        for (int q = 0; q < 4; ++q) {
            int m = m0 + ti + 16 * q;
            D[((size_t)((z << 10) + n) << 10) + m] = 2.f * acc[a][q] - xn - xx[(b << 10) + m];
        }
    }
}

// ---------------- top-20 per row, one wave per row (rows chunk-local) ----------------
__global__ __launch_bounds__(256) void k_topk(const float* __restrict__ D, int* __restrict__ idxo, int b0) {
    const int K = 20;
    int lane = threadIdx.x & 63;
    int rl = blockIdx.x * 4 + (threadIdx.x >> 6);
    const float* row = D + ((size_t)rl << 10);
    float d[16];
#pragma unroll
    for (int j = 0; j < 16; ++j) d[j] = row[lane + 64 * j];
    int rg = (b0 << 10) + rl;
    for (int it = 0; it < K; ++it) {
        float bv = d[0]; int bj = 0;
#pragma unroll
        for (int j = 1; j < 16; ++j) if (d[j] > bv) { bv = d[j]; bj = j; }
        int bm = lane + (bj << 6);
        for (int off = 32; off > 0; off >>= 1) {
            float ov = __shfl_down(bv, off);
            int   om = __shfl_down(bm, off);
            if (ov > bv || (ov == bv && om < bm)) { bv = ov; bm = om; }
        }
        bm = __shfl(bm, 0);
        if (lane == 0) idxo[rg * K + it] = bm;
        if ((bm & 63) == lane) d[bm >> 6] = -FLT_MAX;
    }
}

// ---- V[b][n][o] = X·Wa^T, U[b][n][o] = X·(Wb-Wa)^T ; w is [O][2C] ----
__global__ __launch_bounds__(256) void k_uv(const float* __restrict__ X, const float* __restrict__ w,
                                            float* __restrict__ V, float* __restrict__ U,
                                            int Cp, int C, int O) {
    int n0 = blockIdx.x * 64, o0 = blockIdx.y * 64, b = blockIdx.z;
    __shared__ float Xs[64][33], Was[64][33], Wds[64][33];
    int tid = threadIdx.x, ti = tid & 15, tj = tid >> 4;
    float accv[4][4] = {}, accu[4][4] = {};
    const float* Xb = X + (((size_t)b) << 10) * Cp;
    int W2 = 2 * C;
    for (int c0 = 0; c0 < Cp; c0 += 32) {
        for (int e = tid; e < 2048; e += 256) {
            int row = e >> 5, cc = e & 31, c = c0 + cc;
            Xs[row][cc] = (c < Cp) ? Xb[(size_t)(n0 + row) * Cp + c] : 0.f;
            float wa = 0.f, wd = 0.f;
            if (c < C) {
                float a_ = w[(size_t)(o0 + row) * W2 + c];
                float b_ = w[(size_t)(o0 + row) * W2 + C + c];
                wa = a_; wd = b_ - a_;
            }
            Was[row][cc] = wa; Wds[row][cc] = wd;
        }
        __syncthreads();
#pragma unroll 8
        for (int cc = 0; cc < 32; ++cc) {
            float xv[4], av[4], dv[4];
#pragma unroll
            for (int a = 0; a < 4; ++a) xv[a] = Xs[tj + 16 * a][cc];
#pragma unroll
            for (int q = 0; q < 4; ++q) { av[q] = Was[ti + 16 * q][cc]; dv[q] = Wds[ti + 16 * q][cc]; }
#pragma unroll
            for (int a = 0; a < 4; ++a)
#pragma unroll
                for (int q = 0; q < 4; ++q) { accv[a][q] += xv[a] * av[q]; accu[a][q] += xv[a] * dv[q]; }
        }
        __syncthreads();
    }
#pragma unroll
    for (int a = 0; a < 4; ++a) {
        int n = n0 + tj + 16 * a;
#pragma unroll
        for (int q = 0; q < 4; ++q) {
            int o = o0 + ti + 16 * q;
            size_t oi = ((size_t)((b << 10) + n)) * O + o;
            V[oi] = accv[a][q]; U[oi] = accu[a][q];
        }
    }
}

// ---- out[b][n][o] = max_k leaky(bn(V[b][m_k][o] + U[b][n][o])) ; coalesced rows ----
__global__ __launch_bounds__(256) void k_gmax(const float* __restrict__ V, const float* __restrict__ U,
                                              const int* __restrict__ idx,
                                              const float* __restrict__ gg, const float* __restrict__ bb,
                                              float* __restrict__ Xo, int O) {
    int tid = threadIdx.x;
    int Tn = 256 / O;
    int j = tid / O, o = tid - j * O;
    int pt = blockIdx.x * Tn + j;          // global point = b*1024+n
    int b = pt >> 10;
    float uv = U[(size_t)pt * O + o];
    float gv = gg[o], bv = bb[o];
    const int* ip = idx + (size_t)pt * 20;
    float mx = -FLT_MAX;
    for (int k = 0; k < 20; ++k) {
        int m = ip[k] & 1023;
        float vv = V[(size_t)((b << 10) + m) * O + o];
        float y = gv * ((vv + uv) * BNS_C) + bv;
        y = y > 0.f ? y : 0.2f * y;
        mx = fmaxf(mx, y);
    }
    Xo[(size_t)pt * O + o] = mx;
}

// ---------------- tiled transpose X[b][1024][C] -> T[b][C][1024] ----------------
__global__ __launch_bounds__(256) void k_ht(const float* __restrict__ X, float* __restrict__ T, int C) {
    int b = blockIdx.z;
    int n0 = blockIdx.x * 32, c0 = blockIdx.y * 32;
    __shared__ float t[32][33];
    int tid = threadIdx.x;
    int cc = tid & 31, r = tid >> 5;
#pragma unroll
    for (int p = 0; p < 4; ++p) {
        int row = p * 8 + r;
        t[row][cc] = X[(size_t)((b << 10) + n0 + row) * C + c0 + cc];
    }
    __syncthreads();
#pragma unroll
    for (int p = 0; p < 4; ++p) {
        int crow = p * 8 + r;
        T[((size_t)(b * C + c0 + crow) << 10) + n0 + cc] = t[cc][crow];
    }
}

// ---------------- w5 conv fused with BN+leaky and max/mean pool over n ----------------
__global__ __launch_bounds__(256) void k_final(const float* __restrict__ x1, const float* __restrict__ x2,
                                               const float* __restrict__ x3, const float* __restrict__ x4,
                                               const float* __restrict__ w5,
                                               const float* __restrict__ g5,
                                               const float* __restrict__ b5,
                                               float* __restrict__ p) {
    __shared__ float wt[16][512];
    __shared__ float red[4][16][2];
    int b = blockIdx.y;
    int o0 = blockIdx.x * 16;
    int tid = threadIdx.x;
    for (int e = tid; e < 16 * 512; e += 256) {
        int oi = e >> 9, c = e & 511;
        wt[oi][c] = w5[(size_t)(o0 + oi) * 512 + c];
    }
    __syncthreads();
    float acc[16][4] = {};
    const float* srcs[4] = {x1, x2, x3, x4};
    const int cs[4] = {64, 64, 128, 256};
    int ct = 0;
    for (int s = 0; s < 4; ++s) {
        const float* src = srcs[s] + (((size_t)b * cs[s]) << 10);
        for (int c = 0; c < cs[s]; ++c) {
            float h0 = src[(c << 10) + tid];
            float h1 = src[(c << 10) + tid + 256];
            float h2 = src[(c << 10) + tid + 512];
            float h3 = src[(c << 10) + tid + 768];
#pragma unroll
            for (int oi = 0; oi < 16; ++oi) {
                float wv = wt[oi][ct];
                acc[oi][0] += wv * h0; acc[oi][1] += wv * h1;
                acc[oi][2] += wv * h2; acc[oi][3] += wv * h3;
            }
            ++ct;
        }
    }
    int lane = tid & 63, wid = tid >> 6;
#pragma unroll
    for (int oi = 0; oi < 16; ++oi) {
        float gv = g5[o0 + oi];
        float bv = b5[o0 + oi];
        float mx = -FLT_MAX, sm = 0.f;
#pragma unroll
        for (int j = 0; j < 4; ++j) {
            float y = gv * (acc[oi][j] * BNS_C) + bv;
            y = y > 0.f ? y : 0.2f * y;
            mx = fmaxf(mx, y); sm += y;
        }
        for (int off = 32; off; off >>= 1) {
            mx = fmaxf(mx, __shfl_down(mx, off));
            sm += __shfl_down(sm, off);
        }
        if (lane == 0) { red[wid][oi][0] = mx; red[wid][oi][1] = sm; }
    }
    __syncthreads();
    if (tid < 16) {
        float mx = fmaxf(fmaxf(red[0][tid][0], red[1][tid][0]), fmaxf(red[2][tid][0], red[3][tid][0]));
        float sm = red[0][tid][1] + red[1][tid][1] + red[2][tid][1] + red[3][tid][1];
        p[b * 2048 + o0 + tid] = mx;
        p[b * 2048 + 1024 + o0 + tid] = sm * (1.f / 1024.f);
    }
}

// ---------------- FC: one wave per (r,o); coalesced lane-strided C loop ----------------
__global__ __launch_bounds__(256) void k_fc2(const float* __restrict__ in, const float* __restrict__ w,
                                             const float* __restrict__ gg, const float* __restrict__ bb,
                                             float* __restrict__ out,
                                             int R, int C, int O, int act) {
    int gw = blockIdx.x * 4 + (threadIdx.x >> 6);   // global wave id
    int lane = threadIdx.x & 63;
    if (gw >= R * O) return;
    int r = gw / O, o = gw - r * O;
    const float* ir = in + (size_t)r * C;
    const float* wr = w + (size_t)o * C;
    float s = 0.f;
    for (int c = lane; c < C; c += 64) s += ir[c] * wr[c];
#pragma unroll
    for (int off = 32; off; off >>= 1) s += __shfl_down(s, off);
    if (lane == 0) {
        float y = s;
        if (gg) y = gg[o] * (s * BNS_C) + bb[o];
        if (act == 1) y = y > 0.f ? y : 0.2f * y;
        else if (act == 2) y = 0.5f * y * (1.f + erff(y * 0.70710678118654752f));
        out[gw] = y;
    }
}

extern "C" void kernel_launch(void* const* d_in, const int* in_sizes, int n_in,
                              void* d_out, int out_size, void* d_ws, size_t ws_size,
                              hipStream_t stream) {
    typedef const float* fp;
    fp x  = (fp)d_in[0];
    fp w1 = (fp)d_in[2],  g1 = (fp)d_in[3],  b1 = (fp)d_in[4];
    fp w2 = (fp)d_in[5],  g2 = (fp)d_in[6],  b2 = (fp)d_in[7];
    fp w3 = (fp)d_in[8],  g3 = (fp)d_in[9],  b3 = (fp)d_in[10];
    fp w4 = (fp)d_in[11], g4 = (fp)d_in[12], b4 = (fp)d_in[13];
    fp w5 = (fp)d_in[14], g5 = (fp)d_in[15], b5 = (fp)d_in[16];
    fp wl1 = (fp)d_in[17], g6 = (fp)d_in[18], b6 = (fp)d_in[19];
    fp wl2 = (fp)d_in[20], g7 = (fp)d_in[21], b7 = (fp)d_in[22];
    fp wl21 = (fp)d_in[23], wl22 = (fp)d_in[24];
    fp g8 = (fp)d_in[25], b8 = (fp)d_in[26], wl3 = (fp)d_in[27];

    char* ws = (char*)d_ws;
    size_t off = 0;
    auto alloc = [&](size_t floats) { float* p_ = (float*)(ws + off); off += floats * 4; off = (off + 255) & ~(size_t)255; return p_; };
    float* X0  = alloc(131072);       // 16*1024*8
    float* X1  = alloc(1048576);      // [b][n][64]
    float* X2  = alloc(1048576);
    float* X3  = alloc(2097152);      // [b][n][128]
    float* X4  = alloc(4194304);      // [b][n][256]
    float* xx  = alloc(16384);
    int*   nbr = (int*)alloc(327680); // 16*1024*20
    float* pool = alloc(8388608);     // 32 MiB union: D(8b chunk) | V+U | T1..T4
    float* p   = alloc(32768);
    float* z1  = alloc(4096);
    float* z2  = alloc(2048);
    float* zt  = alloc(1024);
    float* z3  = alloc(512);
    // total ~66 MB

    float* D = pool;                       // 8*1024*1024
    float* V = pool;                       // up to 16384*256
    float* U = pool + 4194304;
    float* T1 = pool;                      // [b][64][1024]
    float* T2 = pool + 1048576;
    float* T3 = pool + 2097152;            // [b][128][1024]
    float* T4 = pool + 4194304;            // [b][256][1024]

    k_xin_t<<<64, 256, 0, stream>>>(x, X0);

    struct Blk { const float* Xin; int Cp, C, O; const float *w, *g, *b; float* Xout; };
    Blk blks[4] = {
        {X0, 8,   6,   64,  w1, g1, b1, X1},
        {X1, 64,  64,  64,  w2, g2, b2, X2},
        {X2, 64,  64,  128, w3, g3, b3, X3},
        {X3, 128, 128, 256, w4, g4, b4, X4},
    };
    for (int i = 0; i < 4; ++i) {
        const Blk& B_ = blks[i];
        k_sqnorm2<<<64, 256, 0, stream>>>(B_.Xin, xx, B_.Cp);
        for (int b0 = 0; b0 < 16; b0 += 8) {
            k_gram2<<<dim3(16, 16, 8), 256, 0, stream>>>(B_.Xin, xx, D, B_.Cp, b0);
            k_topk<<<2048, 256, 0, stream>>>(D, nbr, b0);
        }
        k_uv<<<dim3(16, B_.O / 64, 16), 256, 0, stream>>>(B_.Xin, B_.w, V, U, B_.Cp, B_.C, B_.O);
        int Tn = 256 / B_.O;
        k_gmax<<<16384 / Tn, 256, 0, stream>>>(V, U, nbr, B_.g, B_.b, B_.Xout, B_.O);
    }

    k_ht<<<dim3(32, 2, 16), 256, 0, stream>>>(X1, T1, 64);
    k_ht<<<dim3(32, 2, 16), 256, 0, stream>>>(X2, T2, 64);
    k_ht<<<dim3(32, 4, 16), 256, 0, stream>>>(X3, T3, 128);
    k_ht<<<dim3(32, 8, 16), 256, 0, stream>>>(X4, T4, 256);

    k_final<<<dim3(64, 16), 256, 0, stream>>>(T1, T2, T3, T4, w5, g5, b5, p);

    // wave-per-output FCs: grid = ceil(R*O/4) blocks of 4 waves
    k_fc2<<<(16 * 256 + 3) / 4, 256, 0, stream>>>(p,  wl1, g6, b6, z1, 16, 2048, 256, 1);
    k_fc2<<<(16 * 128 + 3) / 4, 256, 0, stream>>>(z1, wl2, g7, b7, z2, 16, 256, 128, 1);
    k_fc2<<<(16 * 64  + 3) / 4, 256, 0, stream>>>(z2, wl21, nullptr, nullptr, zt, 16, 128, 64, 0);
    k_fc2<<<(16 * 32  + 3) / 4, 256, 0, stream>>>(zt, wl22, g8, b8, z3, 16, 64, 32, 2);
    k_fc2<<<(16 * 90  + 3) / 4, 256, 0, stream>>>(z3, wl3, nullptr, nullptr, (float*)d_out, 16, 32, 90, 0);
}

// Round 7
// 1180.025 us; speedup vs baseline: 3.6485x; 1.0220x over previous
//
#include <hip/hip_runtime.h>
#include <math.h>
#include <float.h>

#define BNS_C 0.9999950000374996f /* 1/sqrt(1+1e-5) */

// ---------------- x[b][6][1024] -> X0[b][n][8] (zero-padded) ----------------
__global__ void k_xin_t(const float* __restrict__ x, float* __restrict__ X0) {
    int i = blockIdx.x * 256 + threadIdx.x;   // over 16384 points
    int b = i >> 10, n = i & 1023;
    const float* xb = x + (((size_t)b * 6) << 10) + n;
    float4* o4 = (float4*)(X0 + ((size_t)i << 3));
    float v0 = xb[0], v1 = xb[1 << 10], v2 = xb[2 << 10];
    float v3 = xb[3 << 10], v4 = xb[4 << 10], v5 = xb[5 << 10];
    o4[0] = make_float4(v0, v1, v2, v3);
    o4[1] = make_float4(v4, v5, 0.f, 0.f);
}

// ---------------- xx[b*1024+n] = sum_c X[b][n][c]^2 (pads are zero) ----------------
__global__ void k_sqnorm2(const float* __restrict__ X, float* __restrict__ xx, int Cp) {
    int i = blockIdx.x * 256 + threadIdx.x;
    const float4* r = (const float4*)(X + (size_t)i * Cp);
    float s = 0.f;
    for (int c4 = 0; c4 < (Cp >> 2); ++c4) {
        float4 v = r[c4];
        s += v.x * v.x + v.y * v.y + v.z * v.z + v.w * v.w;
    }
    xx[i] = s;
}

// ---- D[z][n][m] = 2*X[n]·X[m] - xx[n] - xx[m], X point-major; chunk of 8 batches ----
__global__ __launch_bounds__(256) void k_gram2(const float* __restrict__ X, const float* __restrict__ xx,
                                               float* __restrict__ D, int Cp, int b0) {
    int z = blockIdx.z, b = b0 + z;
    int n0 = blockIdx.y * 64, m0 = blockIdx.x * 64;
    __shared__ float As[64][33], Bs[64][33];
    int tid = threadIdx.x;
    int ti = tid & 15, tj = tid >> 4;
    float acc[4][4] = {};
    const float* Xb = X + (((size_t)b) << 10) * Cp;
    for (int c0 = 0; c0 < Cp; c0 += 32) {
        for (int e = tid; e < 2048; e += 256) {
            int row = e >> 5, cc = e & 31, c = c0 + cc;
            float a = 0.f, bb = 0.f;
            if (c < Cp) {
                a  = Xb[(size_t)(n0 + row) * Cp + c];
                bb = Xb[(size_t)(m0 + row) * Cp + c];
            }
            As[row][cc] = a; Bs[row][cc] = bb;
        }
        __syncthreads();
#pragma unroll 8
        for (int cc = 0; cc < 32; ++cc) {
            float xv[4], yv[4];
#pragma unroll
            for (int a = 0; a < 4; ++a) xv[a] = As[tj + 16 * a][cc];
#pragma unroll
            for (int q = 0; q < 4; ++q) yv[q] = Bs[ti + 16 * q][cc];
#pragma unroll
            for (int a = 0; a < 4; ++a)
#pragma unroll
                for (int q = 0; q < 4; ++q) acc[a][q] += xv[a] * yv[q];
        }
        __syncthreads();
    }
#pragma unroll
    for (int a = 0; a < 4; ++a) {
        int n = n0 + tj + 16 * a;
        float xn = xx[(b << 10) + n];
#pragma unroll
        for (int q = 0; q < 4; ++q) {
            int m = m0 + ti + 16 * q;
            D[((size_t)((z << 10) + n) << 10) + m] = 2.f * acc[a][q] - xn - xx[(b << 10) + m];
        }
    }
}

// ---------------- top-20 per row, one wave per row (rows chunk-local) ----------------
__global__ __launch_bounds__(256) void k_topk(const float* __restrict__ D, int* __restrict__ idxo, int b0) {
    const int K = 20;
    int lane = threadIdx.x & 63;
    int rl = blockIdx.x * 4 + (threadIdx.x >> 6);
    const float* row = D + ((size_t)rl << 10);
    float d[16];
#pragma unroll
    for (int j = 0; j < 16; ++j) d[j] = row[lane + 64 * j];
    int rg = (b0 << 10) + rl;
    for (int it = 0; it < K; ++it) {
        float bv = d[0]; int bj = 0;
#pragma unroll
        for (int j = 1; j < 16; ++j) if (d[j] > bv) { bv = d[j]; bj = j; }
        int bm = lane + (bj << 6);
        for (int off = 32; off > 0; off >>= 1) {
            float ov = __shfl_down(bv, off);
            int   om = __shfl_down(bm, off);
            if (ov > bv || (ov == bv && om < bm)) { bv = ov; bm = om; }
        }
        bm = __shfl(bm, 0);
        if (lane == 0) idxo[rg * K + it] = bm;
        if ((bm & 63) == lane) d[bm >> 6] = -FLT_MAX;
    }
}

// ---- V[b][n][o] = X·Wa^T, U[b][n][o] = X·(Wb-Wa)^T ; w is [O][2C] ----
__global__ __launch_bounds__(256) void k_uv(const float* __restrict__ X, const float* __restrict__ w,
                                            float* __restrict__ V, float* __restrict__ U,
                                            int Cp, int C, int O) {
    int n0 = blockIdx.x * 64, o0 = blockIdx.y * 64, b = blockIdx.z;
    __shared__ float Xs[64][33], Was[64][33], Wds[64][33];
    int tid = threadIdx.x, ti = tid & 15, tj = tid >> 4;
    float accv[4][4] = {}, accu[4][4] = {};
    const float* Xb = X + (((size_t)b) << 10) * Cp;
    int W2 = 2 * C;
    for (int c0 = 0; c0 < Cp; c0 += 32) {
        for (int e = tid; e < 2048; e += 256) {
            int row = e >> 5, cc = e & 31, c = c0 + cc;
            Xs[row][cc] = (c < Cp) ? Xb[(size_t)(n0 + row) * Cp + c] : 0.f;
            float wa = 0.f, wd = 0.f;
            if (c < C) {
                float a_ = w[(size_t)(o0 + row) * W2 + c];
                float b_ = w[(size_t)(o0 + row) * W2 + C + c];
                wa = a_; wd = b_ - a_;
            }
            Was[row][cc] = wa; Wds[row][cc] = wd;
        }
        __syncthreads();
#pragma unroll 8
        for (int cc = 0; cc < 32; ++cc) {
            float xv[4], av[4], dv[4];
#pragma unroll
            for (int a = 0; a < 4; ++a) xv[a] = Xs[tj + 16 * a][cc];
#pragma unroll
            for (int q = 0; q < 4; ++q) { av[q] = Was[ti + 16 * q][cc]; dv[q] = Wds[ti + 16 * q][cc]; }
#pragma unroll
            for (int a = 0; a < 4; ++a)
#pragma unroll
                for (int q = 0; q < 4; ++q) { accv[a][q] += xv[a] * av[q]; accu[a][q] += xv[a] * dv[q]; }
        }
        __syncthreads();
    }
#pragma unroll
    for (int a = 0; a < 4; ++a) {
        int n = n0 + tj + 16 * a;
#pragma unroll
        for (int q = 0; q < 4; ++q) {
            int o = o0 + ti + 16 * q;
            size_t oi = ((size_t)((b << 10) + n)) * O + o;
            V[oi] = accv[a][q]; U[oi] = accu[a][q];
        }
    }
}

// ---- out[b][n][o] = max_k leaky(bn(V[b][m_k][o] + U[b][n][o])) ; coalesced rows ----
__global__ __launch_bounds__(256) void k_gmax(const float* __restrict__ V, const float* __restrict__ U,
                                              const int* __restrict__ idx,
                                              const float* __restrict__ gg, const float* __restrict__ bb,
                                              float* __restrict__ Xo, int O) {
    int tid = threadIdx.x;
    int Tn = 256 / O;
    int j = tid / O, o = tid - j * O;
    int pt = blockIdx.x * Tn + j;          // global point = b*1024+n
    int b = pt >> 10;
    float uv = U[(size_t)pt * O + o];
    float gv = gg[o], bv = bb[o];
    const int* ip = idx + (size_t)pt * 20;
    float mx = -FLT_MAX;
    for (int k = 0; k < 20; ++k) {
        int m = ip[k] & 1023;
        float vv = V[(size_t)((b << 10) + m) * O + o];
        float y = gv * ((vv + uv) * BNS_C) + bv;
        y = y > 0.f ? y : 0.2f * y;
        mx = fmaxf(mx, y);
    }
    Xo[(size_t)pt * O + o] = mx;
}

// ---------------- tiled transpose X[b][1024][C] -> T[b][C][1024] ----------------
__global__ __launch_bounds__(256) void k_ht(const float* __restrict__ X, float* __restrict__ T, int C) {
    int b = blockIdx.z;
    int n0 = blockIdx.x * 32, c0 = blockIdx.y * 32;
    __shared__ float t[32][33];
    int tid = threadIdx.x;
    int cc = tid & 31, r = tid >> 5;
#pragma unroll
    for (int p = 0; p < 4; ++p) {
        int row = p * 8 + r;
        t[row][cc] = X[(size_t)((b << 10) + n0 + row) * C + c0 + cc];
    }
    __syncthreads();
#pragma unroll
    for (int p = 0; p < 4; ++p) {
        int crow = p * 8 + r;
        T[((size_t)(b * C + c0 + crow) << 10) + n0 + cc] = t[cc][crow];
    }
}

// ------- w5 conv fused with BN+leaky and max/mean pool; fmac-dense inner loop -------
// block = (o_tile of 16, batch); thread owns n in {4*tid..4*tid+3} via float4.
// LDS: wts[c][oi] (stride 16, b128-aligned): per c -> 4 broadcast ds_read_b128.
__global__ __launch_bounds__(256) void k_final(const float* __restrict__ x1, const float* __restrict__ x2,
                                               const float* __restrict__ x3, const float* __restrict__ x4,
                                               const float* __restrict__ w5,
                                               const float* __restrict__ g5,
                                               const float* __restrict__ b5,
                                               float* __restrict__ p) {
    __shared__ float wts[512 * 16];        // [c][oi], 32 KB
    __shared__ float red[4][16][2];
    int b = blockIdx.y;
    int o0 = blockIdx.x * 16;
    int tid = threadIdx.x;
    // stage w5 o-strip transposed: e = oi*512 + c (global-coalesced), write wts[c*16+oi]
    for (int e = tid; e < 16 * 512; e += 256) {
        int oi = e >> 9, c = e & 511;
        wts[c * 16 + oi] = w5[(size_t)(o0 + oi) * 512 + c];
    }
    __syncthreads();
    float acc[16][4] = {};
    const float* srcs[4] = {x1, x2, x3, x4};
    const int cs[4] = {64, 64, 128, 256};
    int ct = 0;
    for (int s = 0; s < 4; ++s) {
        const float* src = srcs[s] + (((size_t)b * cs[s]) << 10) + 4 * tid;
        for (int c = 0; c < cs[s]; ++c, ++ct) {
            const float4 h = *(const float4*)(src + (c << 10));
            const float4 w0 = *(const float4*)(wts + ct * 16);
            const float4 w1 = *(const float4*)(wts + ct * 16 + 4);
            const float4 w2 = *(const float4*)(wts + ct * 16 + 8);
            const float4 w3 = *(const float4*)(wts + ct * 16 + 12);
            const float wv[16] = {w0.x, w0.y, w0.z, w0.w, w1.x, w1.y, w1.z, w1.w,
                                  w2.x, w2.y, w2.z, w2.w, w3.x, w3.y, w3.z, w3.w};
#pragma unroll
            for (int oi = 0; oi < 16; ++oi) {
                acc[oi][0] += wv[oi] * h.x; acc[oi][1] += wv[oi] * h.y;
                acc[oi][2] += wv[oi] * h.z; acc[oi][3] += wv[oi] * h.w;
            }
        }
    }
    int lane = tid & 63, wid = tid >> 6;
#pragma unroll
    for (int oi = 0; oi < 16; ++oi) {
        float gb = g5[o0 + oi] * BNS_C;
        float bv = b5[o0 + oi];
        float mx = -FLT_MAX, sm = 0.f;
#pragma unroll
        for (int j = 0; j < 4; ++j) {
            float y = gb * acc[oi][j] + bv;
            y = y > 0.f ? y : 0.2f * y;
            mx = fmaxf(mx, y); sm += y;
        }
        for (int off = 32; off; off >>= 1) {
            mx = fmaxf(mx, __shfl_down(mx, off));
            sm += __shfl_down(sm, off);
        }
        if (lane == 0) { red[wid][oi][0] = mx; red[wid][oi][1] = sm; }
    }
    __syncthreads();
    if (tid < 16) {
        float mx = fmaxf(fmaxf(red[0][tid][0], red[1][tid][0]), fmaxf(red[2][tid][0], red[3][tid][0]));
        float sm = red[0][tid][1] + red[1][tid][1] + red[2][tid][1] + red[3][tid][1];
        p[b * 2048 + o0 + tid] = mx;
        p[b * 2048 + 1024 + o0 + tid] = sm * (1.f / 1024.f);
    }
}

// ---------------- FC: one wave per (r,o); coalesced lane-strided C loop ----------------
__global__ __launch_bounds__(256) void k_fc2(const float* __restrict__ in, const float* __restrict__ w,
                                             const float* __restrict__ gg, const float* __restrict__ bb,
                                             float* __restrict__ out,
                                             int R, int C, int O, int act) {
    int gw = blockIdx.x * 4 + (threadIdx.x >> 6);   // global wave id
    int lane = threadIdx.x & 63;
    if (gw >= R * O) return;
    int r = gw / O, o = gw - r * O;
    const float* ir = in + (size_t)r * C;
    const float* wr = w + (size_t)o * C;
    float s = 0.f;
    for (int c = lane; c < C; c += 64) s += ir[c] * wr[c];
#pragma unroll
    for (int off = 32; off; off >>= 1) s += __shfl_down(s, off);
    if (lane == 0) {
        float y = s;
        if (gg) y = gg[o] * (s * BNS_C) + bb[o];
        if (act == 1) y = y > 0.f ? y : 0.2f * y;
        else if (act == 2) y = 0.5f * y * (1.f + erff(y * 0.70710678118654752f));
        out[gw] = y;
    }
}

extern "C" void kernel_launch(void* const* d_in, const int* in_sizes, int n_in,
                              void* d_out, int out_size, void* d_ws, size_t ws_size,
                              hipStream_t stream) {
    typedef const float* fp;
    fp x  = (fp)d_in[0];
    fp w1 = (fp)d_in[2],  g1 = (fp)d_in[3],  b1 = (fp)d_in[4];
    fp w2 = (fp)d_in[5],  g2 = (fp)d_in[6],  b2 = (fp)d_in[7];
    fp w3 = (fp)d_in[8],  g3 = (fp)d_in[9],  b3 = (fp)d_in[10];
    fp w4 = (fp)d_in[11], g4 = (fp)d_in[12], b4 = (fp)d_in[13];
    fp w5 = (fp)d_in[14], g5 = (fp)d_in[15], b5 = (fp)d_in[16];
    fp wl1 = (fp)d_in[17], g6 = (fp)d_in[18], b6 = (fp)d_in[19];
    fp wl2 = (fp)d_in[20], g7 = (fp)d_in[21], b7 = (fp)d_in[22];
    fp wl21 = (fp)d_in[23], wl22 = (fp)d_in[24];
    fp g8 = (fp)d_in[25], b8 = (fp)d_in[26], wl3 = (fp)d_in[27];

    char* ws = (char*)d_ws;
    size_t off = 0;
    auto alloc = [&](size_t floats) { float* p_ = (float*)(ws + off); off += floats * 4; off = (off + 255) & ~(size_t)255; return p_; };
    float* X0  = alloc(131072);       // 16*1024*8
    float* X1  = alloc(1048576);      // [b][n][64]
    float* X2  = alloc(1048576);
    float* X3  = alloc(2097152);      // [b][n][128]
    float* X4  = alloc(4194304);      // [b][n][256]
    float* xx  = alloc(16384);
    int*   nbr = (int*)alloc(327680); // 16*1024*20
    float* pool = alloc(8388608);     // 32 MiB union: D(8b chunk) | V+U | T1..T4
    float* p   = alloc(32768);
    float* z1  = alloc(4096);
    float* z2  = alloc(2048);
    float* zt  = alloc(1024);
    float* z3  = alloc(512);
    // total ~66 MB

    float* D = pool;                       // 8*1024*1024
    float* V = pool;                       // up to 16384*256
    float* U = pool + 4194304;
    float* T1 = pool;                      // [b][64][1024]
    float* T2 = pool + 1048576;
    float* T3 = pool + 2097152;            // [b][128][1024]
    float* T4 = pool + 4194304;            // [b][256][1024]

    k_xin_t<<<64, 256, 0, stream>>>(x, X0);

    struct Blk { const float* Xin; int Cp, C, O; const float *w, *g, *b; float* Xout; };
    Blk blks[4] = {
        {X0, 8,   6,   64,  w1, g1, b1, X1},
        {X1, 64,  64,  64,  w2, g2, b2, X2},
        {X2, 64,  64,  128, w3, g3, b3, X3},
        {X3, 128, 128, 256, w4, g4, b4, X4},
    };
    for (int i = 0; i < 4; ++i) {
        const Blk& B_ = blks[i];
        k_sqnorm2<<<64, 256, 0, stream>>>(B_.Xin, xx, B_.Cp);
        for (int b0 = 0; b0 < 16; b0 += 8) {
            k_gram2<<<dim3(16, 16, 8), 256, 0, stream>>>(B_.Xin, xx, D, B_.Cp, b0);
            k_topk<<<2048, 256, 0, stream>>>(D, nbr, b0);
        }
        k_uv<<<dim3(16, B_.O / 64, 16), 256, 0, stream>>>(B_.Xin, B_.w, V, U, B_.Cp, B_.C, B_.O);
        int Tn = 256 / B_.O;
        k_gmax<<<16384 / Tn, 256, 0, stream>>>(V, U, nbr, B_.g, B_.b, B_.Xout, B_.O);
    }

    k_ht<<<dim3(32, 2, 16), 256, 0, stream>>>(X1, T1, 64);
    k_ht<<<dim3(32, 2, 16), 256, 0, stream>>>(X2, T2, 64);
    k_ht<<<dim3(32, 4, 16), 256, 0, stream>>>(X3, T3, 128);
    k_ht<<<dim3(32, 8, 16), 256, 0, stream>>>(X4, T4, 256);

    k_final<<<dim3(64, 16), 256, 0, stream>>>(T1, T2, T3, T4, w5, g5, b5, p);

    // wave-per-output FCs: grid = ceil(R*O/4) blocks of 4 waves
    k_fc2<<<(16 * 256 + 3) / 4, 256, 0, stream>>>(p,  wl1, g6, b6, z1, 16, 2048, 256, 1);
    k_fc2<<<(16 * 128 + 3) / 4, 256, 0, stream>>>(z1, wl2, g7, b7, z2, 16, 256, 128, 1);
    k_fc2<<<(16 * 64  + 3) / 4, 256, 0, stream>>>(z2, wl21, nullptr, nullptr, zt, 16, 128, 64, 0);
    k_fc2<<<(16 * 32  + 3) / 4, 256, 0, stream>>>(zt, wl22, g8, b8, z3, 16, 64, 32, 2);
    k_fc2<<<(16 * 90  + 3) / 4, 256, 0, stream>>>(z3, wl3, nullptr, nullptr, (float*)d_out, 16, 32, 90, 0);
}

// Round 8
// 1092.753 us; speedup vs baseline: 3.9399x; 1.0799x over previous
//
#include <hip/hip_runtime.h>
#include <math.h>
#include <float.h>

#define BNS_C 0.9999950000374996f /* 1/sqrt(1+1e-5) */

// ------- x[b][6][1024] -> X0[b][n][8] (zero-padded) + xx norms -------
__global__ void k_xin_t(const float* __restrict__ x, float* __restrict__ X0, float* __restrict__ xx) {
    int i = blockIdx.x * 256 + threadIdx.x;   // over 16384 points
    int b = i >> 10, n = i & 1023;
    const float* xb = x + (((size_t)b * 6) << 10) + n;
    float4* o4 = (float4*)(X0 + ((size_t)i << 3));
    float v0 = xb[0], v1 = xb[1 << 10], v2 = xb[2 << 10];
    float v3 = xb[3 << 10], v4 = xb[4 << 10], v5 = xb[5 << 10];
    o4[0] = make_float4(v0, v1, v2, v3);
    o4[1] = make_float4(v4, v5, 0.f, 0.f);
    xx[i] = v0*v0 + v1*v1 + v2*v2 + v3*v3 + v4*v4 + v5*v5;
}

// ---- D[z][n][m] = 2*X[n]·X[m] - xx[n] - xx[m], X point-major; z over chunk ----
__global__ __launch_bounds__(256) void k_gram2(const float* __restrict__ X, const float* __restrict__ xx,
                                               float* __restrict__ D, int Cp, int b0) {
    int z = blockIdx.z, b = b0 + z;
    int n0 = blockIdx.y * 64, m0 = blockIdx.x * 64;
    __shared__ float As[64][33], Bs[64][33];
    int tid = threadIdx.x;
    int ti = tid & 15, tj = tid >> 4;
    float acc[4][4] = {};
    const float* Xb = X + (((size_t)b) << 10) * Cp;
    for (int c0 = 0; c0 < Cp; c0 += 32) {
        for (int e = tid; e < 2048; e += 256) {
            int row = e >> 5, cc = e & 31, c = c0 + cc;
            float a = 0.f, bb = 0.f;
            if (c < Cp) {
                a  = Xb[(size_t)(n0 + row) * Cp + c];
                bb = Xb[(size_t)(m0 + row) * Cp + c];
            }
            As[row][cc] = a; Bs[row][cc] = bb;
        }
        __syncthreads();
#pragma unroll 8
        for (int cc = 0; cc < 32; ++cc) {
            float xv[4], yv[4];
#pragma unroll
            for (int a = 0; a < 4; ++a) xv[a] = As[tj + 16 * a][cc];
#pragma unroll
            for (int q = 0; q < 4; ++q) yv[q] = Bs[ti + 16 * q][cc];
#pragma unroll
            for (int a = 0; a < 4; ++a)
#pragma unroll
                for (int q = 0; q < 4; ++q) acc[a][q] += xv[a] * yv[q];
        }
        __syncthreads();
    }
#pragma unroll
    for (int a = 0; a < 4; ++a) {
        int n = n0 + tj + 16 * a;
        float xn = xx[(b << 10) + n];
#pragma unroll
        for (int q = 0; q < 4; ++q) {
            int m = m0 + ti + 16 * q;
            D[((size_t)((z << 10) + n) << 10) + m] = 2.f * acc[a][q] - xn - xx[(b << 10) + m];
        }
    }
}

// ---------------- top-20 per row, one wave per row (rows chunk-local) ----------------
__global__ __launch_bounds__(256) void k_topk(const float* __restrict__ D, int* __restrict__ idxo, int b0) {
    const int K = 20;
    int lane = threadIdx.x & 63;
    int rl = blockIdx.x * 4 + (threadIdx.x >> 6);
    const float* row = D + ((size_t)rl << 10);
    float d[16];
#pragma unroll
    for (int j = 0; j < 16; ++j) d[j] = row[lane + 64 * j];
    int rg = (b0 << 10) + rl;
    for (int it = 0; it < K; ++it) {
        float bv = d[0]; int bj = 0;
#pragma unroll
        for (int j = 1; j < 16; ++j) if (d[j] > bv) { bv = d[j]; bj = j; }
        int bm = lane + (bj << 6);
        for (int off = 32; off > 0; off >>= 1) {
            float ov = __shfl_down(bv, off);
            int   om = __shfl_down(bm, off);
            if (ov > bv || (ov == bv && om < bm)) { bv = ov; bm = om; }
        }
        bm = __shfl(bm, 0);
        if (lane == 0) idxo[rg * K + it] = bm;
        if ((bm & 63) == lane) d[bm >> 6] = -FLT_MAX;
    }
}

// ---- V[b][n][o] = X·Wa^T, U[b][n][o] = X·(Wb-Wa)^T ; w is [O][2C] ----
__global__ __launch_bounds__(256) void k_uv(const float* __restrict__ X, const float* __restrict__ w,
                                            float* __restrict__ V, float* __restrict__ U,
                                            int Cp, int C, int O) {
    int n0 = blockIdx.x * 64, o0 = blockIdx.y * 64, b = blockIdx.z;
    __shared__ float Xs[64][33], Was[64][33], Wds[64][33];
    int tid = threadIdx.x, ti = tid & 15, tj = tid >> 4;
    float accv[4][4] = {}, accu[4][4] = {};
    const float* Xb = X + (((size_t)b) << 10) * Cp;
    int W2 = 2 * C;
    for (int c0 = 0; c0 < Cp; c0 += 32) {
        for (int e = tid; e < 2048; e += 256) {
            int row = e >> 5, cc = e & 31, c = c0 + cc;
            Xs[row][cc] = (c < Cp) ? Xb[(size_t)(n0 + row) * Cp + c] : 0.f;
            float wa = 0.f, wd = 0.f;
            if (c < C) {
                float a_ = w[(size_t)(o0 + row) * W2 + c];
                float b_ = w[(size_t)(o0 + row) * W2 + C + c];
                wa = a_; wd = b_ - a_;
            }
            Was[row][cc] = wa; Wds[row][cc] = wd;
        }
        __syncthreads();
#pragma unroll 8
        for (int cc = 0; cc < 32; ++cc) {
            float xv[4], av[4], dv[4];
#pragma unroll
            for (int a = 0; a < 4; ++a) xv[a] = Xs[tj + 16 * a][cc];
#pragma unroll
            for (int q = 0; q < 4; ++q) { av[q] = Was[ti + 16 * q][cc]; dv[q] = Wds[ti + 16 * q][cc]; }
#pragma unroll
            for (int a = 0; a < 4; ++a)
#pragma unroll
                for (int q = 0; q < 4; ++q) { accv[a][q] += xv[a] * av[q]; accu[a][q] += xv[a] * dv[q]; }
        }
        __syncthreads();
    }
#pragma unroll
    for (int a = 0; a < 4; ++a) {
        int n = n0 + tj + 16 * a;
#pragma unroll
        for (int q = 0; q < 4; ++q) {
            int o = o0 + ti + 16 * q;
            size_t oi = ((size_t)((b << 10) + n)) * O + o;
            V[oi] = accv[a][q]; U[oi] = accu[a][q];
        }
    }
}

// ---- out[b][n][o] = max_k leaky(bn(V[m_k]+U[n])) ; also writes xx[pt]=sum_o out^2 ----
__global__ __launch_bounds__(256) void k_gmax(const float* __restrict__ V, const float* __restrict__ U,
                                              const int* __restrict__ idx,
                                              const float* __restrict__ gg, const float* __restrict__ bb,
                                              float* __restrict__ Xo, float* __restrict__ xx, int O) {
    __shared__ float sxx[4];
    int tid = threadIdx.x;
    int Tn = 256 / O;
    int j = tid / O, o = tid - j * O;
    int pt = blockIdx.x * Tn + j;          // global point = b*1024+n
    int b = pt >> 10;
    float uv = U[(size_t)pt * O + o];
    float gv = gg[o], bv = bb[o];
    const int* ip = idx + (size_t)pt * 20;
    float mx = -FLT_MAX;
    for (int k = 0; k < 20; ++k) {
        int m = ip[k] & 1023;
        float vv = V[(size_t)((b << 10) + m) * O + o];
        float y = gv * ((vv + uv) * BNS_C) + bv;
        y = y > 0.f ? y : 0.2f * y;
        mx = fmaxf(mx, y);
    }
    Xo[(size_t)pt * O + o] = mx;
    // per-point squared-norm for the next block's gram (O is a multiple of 64)
    float s = mx * mx;
#pragma unroll
    for (int off = 32; off; off >>= 1) s += __shfl_down(s, off);
    int wid = tid >> 6, lane = tid & 63;
    if (lane == 0) sxx[wid] = s;
    __syncthreads();
    if (o == 0) {
        int Wpp = O >> 6;
        float t = 0.f;
        for (int w = 0; w < Wpp; ++w) t += sxx[j * Wpp + w];
        xx[pt] = t;
    }
}

// ------- merged transpose: all four X[b][1024][C] -> T[b][C][1024] -------
__global__ __launch_bounds__(256) void k_ht_all(const float* __restrict__ X1, const float* __restrict__ X2,
                                                const float* __restrict__ X3, const float* __restrict__ X4,
                                                float* __restrict__ T1, float* __restrict__ T2,
                                                float* __restrict__ T3, float* __restrict__ T4) {
    int b = blockIdx.z;
    int ct = blockIdx.y;
    int n0 = blockIdx.x * 32;
    const float* X; float* T; int C, c0;
    if (ct < 2)      { X = X1; T = T1; C = 64;  c0 = ct * 32; }
    else if (ct < 4) { X = X2; T = T2; C = 64;  c0 = (ct - 2) * 32; }
    else if (ct < 8) { X = X3; T = T3; C = 128; c0 = (ct - 4) * 32; }
    else             { X = X4; T = T4; C = 256; c0 = (ct - 8) * 32; }
    __shared__ float t[32][33];
    int tid = threadIdx.x;
    int cc = tid & 31, r = tid >> 5;
#pragma unroll
    for (int p = 0; p < 4; ++p) {
        int row = p * 8 + r;
        t[row][cc] = X[(size_t)((b << 10) + n0 + row) * C + c0 + cc];
    }
    __syncthreads();
#pragma unroll
    for (int p = 0; p < 4; ++p) {
        int crow = p * 8 + r;
        T[((size_t)(b * C + c0 + crow) << 10) + n0 + cc] = t[cc][crow];
    }
}

// ------- w5 conv fused with BN+leaky and max/mean pool; o-tile=8, LDS 16KB -------
__global__ __launch_bounds__(256) void k_final(const float* __restrict__ x1, const float* __restrict__ x2,
                                               const float* __restrict__ x3, const float* __restrict__ x4,
                                               const float* __restrict__ w5,
                                               const float* __restrict__ g5,
                                               const float* __restrict__ b5,
                                               float* __restrict__ p) {
    __shared__ float wts[512 * 8];         // [c][oi], 16 KB
    __shared__ float red[4][8][2];
    int b = blockIdx.y;
    int o0 = blockIdx.x * 8;
    int tid = threadIdx.x;
    for (int e = tid; e < 8 * 512; e += 256) {
        int oi = e >> 9, c = e & 511;
        wts[c * 8 + oi] = w5[(size_t)(o0 + oi) * 512 + c];
    }
    __syncthreads();
    float acc[8][4] = {};
    const float* srcs[4] = {x1, x2, x3, x4};
    const int cs[4] = {64, 64, 128, 256};
    int ct = 0;
    for (int s = 0; s < 4; ++s) {
        const float* src = srcs[s] + (((size_t)b * cs[s]) << 10) + 4 * tid;
        for (int c = 0; c < cs[s]; ++c, ++ct) {
            const float4 h = *(const float4*)(src + (c << 10));
            const float4 w0 = *(const float4*)(wts + ct * 8);
            const float4 w1 = *(const float4*)(wts + ct * 8 + 4);
            const float wv[8] = {w0.x, w0.y, w0.z, w0.w, w1.x, w1.y, w1.z, w1.w};
#pragma unroll
            for (int oi = 0; oi < 8; ++oi) {
                acc[oi][0] += wv[oi] * h.x; acc[oi][1] += wv[oi] * h.y;
                acc[oi][2] += wv[oi] * h.z; acc[oi][3] += wv[oi] * h.w;
            }
        }
    }
    int lane = tid & 63, wid = tid >> 6;
#pragma unroll
    for (int oi = 0; oi < 8; ++oi) {
        float gb = g5[o0 + oi] * BNS_C;
        float bv = b5[o0 + oi];
        float mx = -FLT_MAX, sm = 0.f;
#pragma unroll
        for (int j = 0; j < 4; ++j) {
            float y = gb * acc[oi][j] + bv;
            y = y > 0.f ? y : 0.2f * y;
            mx = fmaxf(mx, y); sm += y;
        }
        for (int off = 32; off; off >>= 1) {
            mx = fmaxf(mx, __shfl_down(mx, off));
            sm += __shfl_down(sm, off);
        }
        if (lane == 0) { red[wid][oi][0] = mx; red[wid][oi][1] = sm; }
    }
    __syncthreads();
    if (tid < 8) {
        float mx = fmaxf(fmaxf(red[0][tid][0], red[1][tid][0]), fmaxf(red[2][tid][0], red[3][tid][0]));
        float sm = red[0][tid][1] + red[1][tid][1] + red[2][tid][1] + red[3][tid][1];
        p[b * 2048 + o0 + tid] = mx;
        p[b * 2048 + 1024 + o0 + tid] = sm * (1.f / 1024.f);
    }
}

// ---------------- FC: one wave per (r,o); coalesced lane-strided C loop ----------------
__global__ __launch_bounds__(256) void k_fc2(const float* __restrict__ in, const float* __restrict__ w,
                                             const float* __restrict__ gg, const float* __restrict__ bb,
                                             float* __restrict__ out,
                                             int R, int C, int O, int act) {
    int gw = blockIdx.x * 4 + (threadIdx.x >> 6);   // global wave id
    int lane = threadIdx.x & 63;
    if (gw >= R * O) return;
    int r = gw / O, o = gw - r * O;
    const float* ir = in + (size_t)r * C;
    const float* wr = w + (size_t)o * C;
    float s = 0.f;
    for (int c = lane; c < C; c += 64) s += ir[c] * wr[c];
#pragma unroll
    for (int off = 32; off; off >>= 1) s += __shfl_down(s, off);
    if (lane == 0) {
        float y = s;
        if (gg) y = gg[o] * (s * BNS_C) + bb[o];
        if (act == 1) y = y > 0.f ? y : 0.2f * y;
        else if (act == 2) y = 0.5f * y * (1.f + erff(y * 0.70710678118654752f));
        out[gw] = y;
    }
}

extern "C" void kernel_launch(void* const* d_in, const int* in_sizes, int n_in,
                              void* d_out, int out_size, void* d_ws, size_t ws_size,
                              hipStream_t stream) {
    typedef const float* fp;
    fp x  = (fp)d_in[0];
    fp w1 = (fp)d_in[2],  g1 = (fp)d_in[3],  b1 = (fp)d_in[4];
    fp w2 = (fp)d_in[5],  g2 = (fp)d_in[6],  b2 = (fp)d_in[7];
    fp w3 = (fp)d_in[8],  g3 = (fp)d_in[9],  b3 = (fp)d_in[10];
    fp w4 = (fp)d_in[11], g4 = (fp)d_in[12], b4 = (fp)d_in[13];
    fp w5 = (fp)d_in[14], g5 = (fp)d_in[15], b5 = (fp)d_in[16];
    fp wl1 = (fp)d_in[17], g6 = (fp)d_in[18], b6 = (fp)d_in[19];
    fp wl2 = (fp)d_in[20], g7 = (fp)d_in[21], b7 = (fp)d_in[22];
    fp wl21 = (fp)d_in[23], wl22 = (fp)d_in[24];
    fp g8 = (fp)d_in[25], b8 = (fp)d_in[26], wl3 = (fp)d_in[27];

    char* ws = (char*)d_ws;
    size_t off = 0;
    auto alloc = [&](size_t floats) { float* p_ = (float*)(ws + off); off += floats * 4; off = (off + 255) & ~(size_t)255; return p_; };
    float* X0  = alloc(131072);       // 16*1024*8
    float* X1  = alloc(1048576);      // [b][n][64]
    float* X2  = alloc(1048576);
    float* X3  = alloc(2097152);      // [b][n][128]
    float* X4  = alloc(4194304);      // [b][n][256]
    float* xx  = alloc(16384);
    int*   nbr = (int*)alloc(327680); // 16*1024*20
    float* p   = alloc(32768);
    float* z1  = alloc(4096);
    float* z2  = alloc(2048);
    float* zt  = alloc(1024);
    float* z3  = alloc(512);
    // pool takes the remainder: union of D | V+U | T1..T4
    size_t poolAvail = (ws_size > off) ? (ws_size - off) / 4 : 0;
    int fullD = poolAvail >= 16777216;                 // 64 MB full distance tensor
    float* pool = alloc(fullD ? 16777216 : 8388608);

    float* D = pool;
    float* V = pool;
    float* U = pool + 4194304;
    float* T1 = pool;
    float* T2 = pool + 1048576;
    float* T3 = pool + 2097152;
    float* T4 = pool + 4194304;

    k_xin_t<<<64, 256, 0, stream>>>(x, X0, xx);

    struct Blk { const float* Xin; int Cp, C, O; const float *w, *g, *b; float* Xout; };
    Blk blks[4] = {
        {X0, 8,   6,   64,  w1, g1, b1, X1},
        {X1, 64,  64,  64,  w2, g2, b2, X2},
        {X2, 64,  64,  128, w3, g3, b3, X3},
        {X3, 128, 128, 256, w4, g4, b4, X4},
    };
    for (int i = 0; i < 4; ++i) {
        const Blk& B_ = blks[i];
        if (fullD) {
            k_gram2<<<dim3(16, 16, 16), 256, 0, stream>>>(B_.Xin, xx, D, B_.Cp, 0);
            k_topk<<<4096, 256, 0, stream>>>(D, nbr, 0);
        } else {
            for (int b0 = 0; b0 < 16; b0 += 8) {
                k_gram2<<<dim3(16, 16, 8), 256, 0, stream>>>(B_.Xin, xx, D, B_.Cp, b0);
                k_topk<<<2048, 256, 0, stream>>>(D, nbr, b0);
            }
        }
        k_uv<<<dim3(16, B_.O / 64, 16), 256, 0, stream>>>(B_.Xin, B_.w, V, U, B_.Cp, B_.C, B_.O);
        int Tn = 256 / B_.O;
        k_gmax<<<16384 / Tn, 256, 0, stream>>>(V, U, nbr, B_.g, B_.b, B_.Xout, xx, B_.O);
    }

    k_ht_all<<<dim3(32, 16, 16), 256, 0, stream>>>(X1, X2, X3, X4, T1, T2, T3, T4);

    k_final<<<dim3(128, 16), 256, 0, stream>>>(T1, T2, T3, T4, w5, g5, b5, p);

    k_fc2<<<(16 * 256 + 3) / 4, 256, 0, stream>>>(p,  wl1, g6, b6, z1, 16, 2048, 256, 1);
    k_fc2<<<(16 * 128 + 3) / 4, 256, 0, stream>>>(z1, wl2, g7, b7, z2, 16, 256, 128, 1);
    k_fc2<<<(16 * 64  + 3) / 4, 256, 0, stream>>>(z2, wl21, nullptr, nullptr, zt, 16, 128, 64, 0);
    k_fc2<<<(16 * 32  + 3) / 4, 256, 0, stream>>>(zt, wl22, g8, b8, z3, 16, 64, 32, 2);
    k_fc2<<<(16 * 90  + 3) / 4, 256, 0, stream>>>(z3, wl3, nullptr, nullptr, (float*)d_out, 16, 32, 90, 0);
}

// Round 9
// 1002.440 us; speedup vs baseline: 4.2949x; 1.0901x over previous
//
#include <hip/hip_runtime.h>
#include <math.h>
#include <float.h>

#define BNS_C 0.9999950000374996f /* 1/sqrt(1+1e-5) */

typedef __bf16 bf8 __attribute__((ext_vector_type(8)));
typedef float f4 __attribute__((ext_vector_type(4)));
union I4BF8 { int4 i; bf8 b; };

static __device__ __forceinline__ unsigned short f2bf(float f) {
    unsigned u = __float_as_uint(f);
    u += 0x7fff + ((u >> 16) & 1);          // round-to-nearest-even
    return (unsigned short)(u >> 16);
}

// ------- x[b][6][1024] -> X0[b][n][8] (zero-padded) + xx norms -------
__global__ void k_xin_t(const float* __restrict__ x, float* __restrict__ X0, float* __restrict__ xx) {
    int i = blockIdx.x * 256 + threadIdx.x;   // over 16384 points
    int b = i >> 10, n = i & 1023;
    const float* xb = x + (((size_t)b * 6) << 10) + n;
    float4* o4 = (float4*)(X0 + ((size_t)i << 3));
    float v0 = xb[0], v1 = xb[1 << 10], v2 = xb[2 << 10];
    float v3 = xb[3 << 10], v4 = xb[4 << 10], v5 = xb[5 << 10];
    o4[0] = make_float4(v0, v1, v2, v3);
    o4[1] = make_float4(v4, v5, 0.f, 0.f);
    xx[i] = v0*v0 + v1*v1 + v2*v2 + v3*v3 + v4*v4 + v5*v5;
}

// ---- D[z][n][m] = 2*X[n]·X[m] - xx[n] - xx[m], X point-major; z over chunk ----
__global__ __launch_bounds__(256) void k_gram2(const float* __restrict__ X, const float* __restrict__ xx,
                                               float* __restrict__ D, int Cp, int b0) {
    int z = blockIdx.z, b = b0 + z;
    int n0 = blockIdx.y * 64, m0 = blockIdx.x * 64;
    __shared__ float As[64][33], Bs[64][33];
    int tid = threadIdx.x;
    int ti = tid & 15, tj = tid >> 4;
    float acc[4][4] = {};
    const float* Xb = X + (((size_t)b) << 10) * Cp;
    for (int c0 = 0; c0 < Cp; c0 += 32) {
        for (int e = tid; e < 2048; e += 256) {
            int row = e >> 5, cc = e & 31, c = c0 + cc;
            float a = 0.f, bb = 0.f;
            if (c < Cp) {
                a  = Xb[(size_t)(n0 + row) * Cp + c];
                bb = Xb[(size_t)(m0 + row) * Cp + c];
            }
            As[row][cc] = a; Bs[row][cc] = bb;
        }
        __syncthreads();
#pragma unroll 8
        for (int cc = 0; cc < 32; ++cc) {
            float xv[4], yv[4];
#pragma unroll
            for (int a = 0; a < 4; ++a) xv[a] = As[tj + 16 * a][cc];
#pragma unroll
            for (int q = 0; q < 4; ++q) yv[q] = Bs[ti + 16 * q][cc];
#pragma unroll
            for (int a = 0; a < 4; ++a)
#pragma unroll
                for (int q = 0; q < 4; ++q) acc[a][q] += xv[a] * yv[q];
        }
        __syncthreads();
    }
#pragma unroll
    for (int a = 0; a < 4; ++a) {
        int n = n0 + tj + 16 * a;
        float xn = xx[(b << 10) + n];
#pragma unroll
        for (int q = 0; q < 4; ++q) {
            int m = m0 + ti + 16 * q;
            D[((size_t)((z << 10) + n) << 10) + m] = 2.f * acc[a][q] - xn - xx[(b << 10) + m];
        }
    }
}

// ---------------- top-20 per row, one wave per row (rows chunk-local) ----------------
__global__ __launch_bounds__(256) void k_topk(const float* __restrict__ D, int* __restrict__ idxo, int b0) {
    const int K = 20;
    int lane = threadIdx.x & 63;
    int rl = blockIdx.x * 4 + (threadIdx.x >> 6);
    const float* row = D + ((size_t)rl << 10);
    float d[16];
#pragma unroll
    for (int j = 0; j < 16; ++j) d[j] = row[lane + 64 * j];
    int rg = (b0 << 10) + rl;
    for (int it = 0; it < K; ++it) {
        float bv = d[0]; int bj = 0;
#pragma unroll
        for (int j = 1; j < 16; ++j) if (d[j] > bv) { bv = d[j]; bj = j; }
        int bm = lane + (bj << 6);
        for (int off = 32; off > 0; off >>= 1) {
            float ov = __shfl_down(bv, off);
            int   om = __shfl_down(bm, off);
            if (ov > bv || (ov == bv && om < bm)) { bv = ov; bm = om; }
        }
        bm = __shfl(bm, 0);
        if (lane == 0) idxo[rg * K + it] = bm;
        if ((bm & 63) == lane) d[bm >> 6] = -FLT_MAX;
    }
}

// ---- V[b][n][o] = X·Wa^T, U[b][n][o] = X·(Wb-Wa)^T ; w is [O][2C] ----
__global__ __launch_bounds__(256) void k_uv(const float* __restrict__ X, const float* __restrict__ w,
                                            float* __restrict__ V, float* __restrict__ U,
                                            int Cp, int C, int O) {
    int n0 = blockIdx.x * 64, o0 = blockIdx.y * 64, b = blockIdx.z;
    __shared__ float Xs[64][33], Was[64][33], Wds[64][33];
    int tid = threadIdx.x, ti = tid & 15, tj = tid >> 4;
    float accv[4][4] = {}, accu[4][4] = {};
    const float* Xb = X + (((size_t)b) << 10) * Cp;
    int W2 = 2 * C;
    for (int c0 = 0; c0 < Cp; c0 += 32) {
        for (int e = tid; e < 2048; e += 256) {
            int row = e >> 5, cc = e & 31, c = c0 + cc;
            Xs[row][cc] = (c < Cp) ? Xb[(size_t)(n0 + row) * Cp + c] : 0.f;
            float wa = 0.f, wd = 0.f;
            if (c < C) {
                float a_ = w[(size_t)(o0 + row) * W2 + c];
                float b_ = w[(size_t)(o0 + row) * W2 + C + c];
                wa = a_; wd = b_ - a_;
            }
            Was[row][cc] = wa; Wds[row][cc] = wd;
        }
        __syncthreads();
#pragma unroll 8
        for (int cc = 0; cc < 32; ++cc) {
            float xv[4], av[4], dv[4];
#pragma unroll
            for (int a = 0; a < 4; ++a) xv[a] = Xs[tj + 16 * a][cc];
#pragma unroll
            for (int q = 0; q < 4; ++q) { av[q] = Was[ti + 16 * q][cc]; dv[q] = Wds[ti + 16 * q][cc]; }
#pragma unroll
            for (int a = 0; a < 4; ++a)
#pragma unroll
                for (int q = 0; q < 4; ++q) { accv[a][q] += xv[a] * av[q]; accu[a][q] += xv[a] * dv[q]; }
        }
        __syncthreads();
    }
#pragma unroll
    for (int a = 0; a < 4; ++a) {
        int n = n0 + tj + 16 * a;
#pragma unroll
        for (int q = 0; q < 4; ++q) {
            int o = o0 + ti + 16 * q;
            size_t oi = ((size_t)((b << 10) + n)) * O + o;
            V[oi] = accv[a][q]; U[oi] = accu[a][q];
        }
    }
}

// ---- out[b][n][o] = max_k leaky(bn(V[m_k]+U[n])); writes f32 Xo, bf16 HB col-slice, xx ----
__global__ __launch_bounds__(256) void k_gmax(const float* __restrict__ V, const float* __restrict__ U,
                                              const int* __restrict__ idx,
                                              const float* __restrict__ gg, const float* __restrict__ bb,
                                              float* __restrict__ Xo, float* __restrict__ xx,
                                              unsigned short* __restrict__ HB, int coff, int O) {
    __shared__ float sxx[4];
    int tid = threadIdx.x;
    int Tn = 256 / O;
    int j = tid / O, o = tid - j * O;
    int pt = blockIdx.x * Tn + j;          // global point = b*1024+n
    int b = pt >> 10;
    float uv = U[(size_t)pt * O + o];
    float gv = gg[o], bv = bb[o];
    const int* ip = idx + (size_t)pt * 20;
    float mx = -FLT_MAX;
    for (int k = 0; k < 20; ++k) {
        int m = ip[k] & 1023;
        float vv = V[(size_t)((b << 10) + m) * O + o];
        float y = gv * ((vv + uv) * BNS_C) + bv;
        y = y > 0.f ? y : 0.2f * y;
        mx = fmaxf(mx, y);
    }
    Xo[(size_t)pt * O + o] = mx;
    HB[(size_t)pt * 512 + coff + o] = f2bf(mx);
    // per-point squared-norm for the next block's gram (O is a multiple of 64)
    float s = mx * mx;
#pragma unroll
    for (int off = 32; off; off >>= 1) s += __shfl_down(s, off);
    int wid = tid >> 6, lane = tid & 63;
    if (lane == 0) sxx[wid] = s;
    __syncthreads();
    if (o == 0) {
        int Wpp = O >> 6;
        float t = 0.f;
        for (int w = 0; w < Wpp; ++w) t += sxx[j * Wpp + w];
        xx[pt] = t;
    }
}

// ------- fused MFMA GEMM + BN/leaky + max/mean pool over n; no y materialization -------
// grid (16 o-strips, 16 batches), 4 waves; wave owns 16 o; A = HB[b][n][c] bf16, B = w5.
__global__ __launch_bounds__(256) void k_final_mfma(const unsigned short* __restrict__ HB,
                                                    const float* __restrict__ w5,
                                                    const float* __restrict__ g5,
                                                    const float* __restrict__ b5,
                                                    float* __restrict__ p) {
    int b = blockIdx.y;
    int wv = threadIdx.x >> 6, lane = threadIdx.x & 63;
    int r = lane & 15, q = lane >> 4;
    int o = blockIdx.x * 64 + wv * 16 + r;          // this lane's output column
    // B fragments: Bfr[s] = w5[o][32s + 8q + j], j=0..7 (B[k][n] layout: n=lane&15, k=8q+j)
    bf8 Bfr[16];
    const float* wrow = w5 + (size_t)o * 512 + q * 8;
#pragma unroll
    for (int s = 0; s < 16; ++s) {
        float4 f0 = *(const float4*)(wrow + s * 32);
        float4 f1 = *(const float4*)(wrow + s * 32 + 4);
        I4BF8 u_;
        u_.i.x = f2bf(f0.x) | ((unsigned)f2bf(f0.y) << 16);
        u_.i.y = f2bf(f0.z) | ((unsigned)f2bf(f0.w) << 16);
        u_.i.z = f2bf(f1.x) | ((unsigned)f2bf(f1.y) << 16);
        u_.i.w = f2bf(f1.z) | ((unsigned)f2bf(f1.w) << 16);
        Bfr[s] = u_.b;
    }
    float gb = g5[o] * BNS_C, bv = b5[o];
    const unsigned short* HBb = HB + ((((size_t)b) << 10)) * 512 + q * 8;
    float mx = -FLT_MAX, sm = 0.f;
    for (int g = 0; g < 16; ++g) {
        const unsigned short* a0 = HBb + (size_t)(g * 64 +  0 + r) * 512;
        const unsigned short* a1 = HBb + (size_t)(g * 64 + 16 + r) * 512;
        const unsigned short* a2 = HBb + (size_t)(g * 64 + 32 + r) * 512;
        const unsigned short* a3 = HBb + (size_t)(g * 64 + 48 + r) * 512;
        f4 C0 = {0.f, 0.f, 0.f, 0.f}, C1 = C0, C2 = C0, C3 = C0;
#pragma unroll
        for (int s = 0; s < 16; ++s) {
            I4BF8 A0, A1, A2, A3;
            A0.i = *(const int4*)(a0 + s * 32);
            A1.i = *(const int4*)(a1 + s * 32);
            A2.i = *(const int4*)(a2 + s * 32);
            A3.i = *(const int4*)(a3 + s * 32);
            C0 = __builtin_amdgcn_mfma_f32_16x16x32_bf16(A0.b, Bfr[s], C0, 0, 0, 0);
            C1 = __builtin_amdgcn_mfma_f32_16x16x32_bf16(A1.b, Bfr[s], C1, 0, 0, 0);
            C2 = __builtin_amdgcn_mfma_f32_16x16x32_bf16(A2.b, Bfr[s], C2, 0, 0, 0);
            C3 = __builtin_amdgcn_mfma_f32_16x16x32_bf16(A3.b, Bfr[s], C3, 0, 0, 0);
        }
        // pooling is order-agnostic over n: fold all 16 C values (4 tiles x 4 regs)
#pragma unroll
        for (int e = 0; e < 4; ++e) {
            float y0 = gb * C0[e] + bv; y0 = y0 > 0.f ? y0 : 0.2f * y0; mx = fmaxf(mx, y0); sm += y0;
            float y1 = gb * C1[e] + bv; y1 = y1 > 0.f ? y1 : 0.2f * y1; mx = fmaxf(mx, y1); sm += y1;
            float y2 = gb * C2[e] + bv; y2 = y2 > 0.f ? y2 : 0.2f * y2; mx = fmaxf(mx, y2); sm += y2;
            float y3 = gb * C3[e] + bv; y3 = y3 > 0.f ? y3 : 0.2f * y3; mx = fmaxf(mx, y3); sm += y3;
        }
    }
    // combine the 4 q-groups (lanes +16,+32,+48 share the same o)
    mx = fmaxf(mx, __shfl_down(mx, 32)); sm += __shfl_down(sm, 32);
    mx = fmaxf(mx, __shfl_down(mx, 16)); sm += __shfl_down(sm, 16);
    if (q == 0) {
        p[b * 2048 + o] = mx;
        p[b * 2048 + 1024 + o] = sm * (1.f / 1024.f);
    }
}

// ---------------- FC: one wave per (r,o); coalesced lane-strided C loop ----------------
__global__ __launch_bounds__(256) void k_fc2(const float* __restrict__ in, const float* __restrict__ w,
                                             const float* __restrict__ gg, const float* __restrict__ bb,
                                             float* __restrict__ out,
                                             int R, int C, int O, int act) {
    int gw = blockIdx.x * 4 + (threadIdx.x >> 6);   // global wave id
    int lane = threadIdx.x & 63;
    if (gw >= R * O) return;
    int r = gw / O, o = gw - r * O;
    const float* ir = in + (size_t)r * C;
    const float* wr = w + (size_t)o * C;
    float s = 0.f;
    for (int c = lane; c < C; c += 64) s += ir[c] * wr[c];
#pragma unroll
    for (int off = 32; off; off >>= 1) s += __shfl_down(s, off);
    if (lane == 0) {
        float y = s;
        if (gg) y = gg[o] * (s * BNS_C) + bb[o];
        if (act == 1) y = y > 0.f ? y : 0.2f * y;
        else if (act == 2) y = 0.5f * y * (1.f + erff(y * 0.70710678118654752f));
        out[gw] = y;
    }
}

extern "C" void kernel_launch(void* const* d_in, const int* in_sizes, int n_in,
                              void* d_out, int out_size, void* d_ws, size_t ws_size,
                              hipStream_t stream) {
    typedef const float* fp;
    fp x  = (fp)d_in[0];
    fp w1 = (fp)d_in[2],  g1 = (fp)d_in[3],  b1 = (fp)d_in[4];
    fp w2 = (fp)d_in[5],  g2 = (fp)d_in[6],  b2 = (fp)d_in[7];
    fp w3 = (fp)d_in[8],  g3 = (fp)d_in[9],  b3 = (fp)d_in[10];
    fp w4 = (fp)d_in[11], g4 = (fp)d_in[12], b4 = (fp)d_in[13];
    fp w5 = (fp)d_in[14], g5 = (fp)d_in[15], b5 = (fp)d_in[16];
    fp wl1 = (fp)d_in[17], g6 = (fp)d_in[18], b6 = (fp)d_in[19];
    fp wl2 = (fp)d_in[20], g7 = (fp)d_in[21], b7 = (fp)d_in[22];
    fp wl21 = (fp)d_in[23], wl22 = (fp)d_in[24];
    fp g8 = (fp)d_in[25], b8 = (fp)d_in[26], wl3 = (fp)d_in[27];

    char* ws = (char*)d_ws;
    size_t off = 0;
    auto alloc = [&](size_t floats) { float* p_ = (float*)(ws + off); off += floats * 4; off = (off + 255) & ~(size_t)255; return p_; };
    float* X0  = alloc(131072);       // 16*1024*8
    float* X1  = alloc(1048576);      // [b][n][64]
    float* X2  = alloc(1048576);
    float* X3  = alloc(2097152);      // [b][n][128]
    float* X4  = alloc(4194304);      // [b][n][256]
    float* xx  = alloc(16384);
    int*   nbr = (int*)alloc(327680); // 16*1024*20
    unsigned short* HB = (unsigned short*)alloc(4194304);  // bf16 [16*1024][512] concat feats
    float* p   = alloc(32768);
    float* z1  = alloc(4096);
    float* z2  = alloc(2048);
    float* zt  = alloc(1024);
    float* z3  = alloc(512);
    // pool: union of D | V+U
    size_t poolAvail = (ws_size > off) ? (ws_size - off) / 4 : 0;
    int fullD = poolAvail >= 16777216;                 // 64 MB full distance tensor
    float* pool = alloc(fullD ? 16777216 : 8388608);

    float* D = pool;
    float* V = pool;
    float* U = pool + 4194304;

    k_xin_t<<<64, 256, 0, stream>>>(x, X0, xx);

    struct Blk { const float* Xin; int Cp, C, O, coff; const float *w, *g, *b; float* Xout; };
    Blk blks[4] = {
        {X0, 8,   6,   64,  0,   w1, g1, b1, X1},
        {X1, 64,  64,  64,  64,  w2, g2, b2, X2},
        {X2, 64,  64,  128, 128, w3, g3, b3, X3},
        {X3, 128, 128, 256, 256, w4, g4, b4, X4},
    };
    for (int i = 0; i < 4; ++i) {
        const Blk& B_ = blks[i];
        if (fullD) {
            k_gram2<<<dim3(16, 16, 16), 256, 0, stream>>>(B_.Xin, xx, D, B_.Cp, 0);
            k_topk<<<4096, 256, 0, stream>>>(D, nbr, 0);
        } else {
            for (int b0 = 0; b0 < 16; b0 += 8) {
                k_gram2<<<dim3(16, 16, 8), 256, 0, stream>>>(B_.Xin, xx, D, B_.Cp, b0);
                k_topk<<<2048, 256, 0, stream>>>(D, nbr, b0);
            }
        }
        k_uv<<<dim3(16, B_.O / 64, 16), 256, 0, stream>>>(B_.Xin, B_.w, V, U, B_.Cp, B_.C, B_.O);
        int Tn = 256 / B_.O;
        k_gmax<<<16384 / Tn, 256, 0, stream>>>(V, U, nbr, B_.g, B_.b, B_.Xout, xx, HB, B_.coff, B_.O);
    }

    k_final_mfma<<<dim3(16, 16), 256, 0, stream>>>(HB, w5, g5, b5, p);

    k_fc2<<<(16 * 256 + 3) / 4, 256, 0, stream>>>(p,  wl1, g6, b6, z1, 16, 2048, 256, 1);
    k_fc2<<<(16 * 128 + 3) / 4, 256, 0, stream>>>(z1, wl2, g7, b7, z2, 16, 256, 128, 1);
    k_fc2<<<(16 * 64  + 3) / 4, 256, 0, stream>>>(z2, wl21, nullptr, nullptr, zt, 16, 128, 64, 0);
    k_fc2<<<(16 * 32  + 3) / 4, 256, 0, stream>>>(zt, wl22, g8, b8, z3, 16, 64, 32, 2);
    k_fc2<<<(16 * 90  + 3) / 4, 256, 0, stream>>>(z3, wl3, nullptr, nullptr, (float*)d_out, 16, 32, 90, 0);
}